// Round 3
// baseline (2409.344 us; speedup 1.0000x reference)
//
#include <hip/hip_runtime.h>
#include <hip/hip_bf16.h>
#include <hip/hip_cooperative_groups.h>
#include <math.h>

namespace cg = cooperative_groups;
using bf16 = __hip_bfloat16;

#define H_IMG 128
#define W_IMG 128
#define C_IN  200
#define NCLS  16
#define N0    16384
#define N1    4096
#define N2    1024
#define KNB   16
#define EPS   1e-5f
#define SLOPE 0.01f

#define NBLK  512
#define NTHR  256
#define GSZ   (NBLK * NTHR)   // 131072 threads

__device__ __forceinline__ float leaky(float v) { return v >= 0.f ? v : SLOPE * v; }
__device__ __forceinline__ float lda(const void* p, long i, bool F32) {
    return F32 ? ((const float*)p)[i] : __bfloat162float(((const bf16*)p)[i]);
}

struct Params {
    const void *x; const int *nbr_a, *nbr_b;
    const void *hg,*hb,*hpw,*hpb,*hdw,*hdb;
    const void *e0_g,*e0_b,*e0_wt,*e0_bt,*e0_wo,*e0_bo;
    const void *e1_g,*e1_b,*e1_wt,*e1_bt,*e1_wo,*e1_bo;
    const void *d0_g,*d0_b,*d0_wt,*d0_bt,*d0_wo,*d0_bo;
    const void *tg,*tb,*tpw,*tpb,*tdw,*tdb,*wsw,*wb;
    void* out; float* W;
};

// column stats over an f32 matrix; rep=virtual row replication factor, Pv=virtual row count
__device__ __forceinline__ void stats_dev(const float* X, long ld, long col, int P, int rep, int Pv,
                                          const void* g, const void* bb, float* alpha, float* beta,
                                          int c, int t, float* smA, float* smB, bool F32) {
    float s = 0.f, s2 = 0.f;
    for (int r = t; r < P; r += NTHR) { float v = X[(long)r * ld + col]; s += v; s2 += v * v; }
    smA[t] = s; smB[t] = s2; __syncthreads();
    for (int k = 128; k > 0; k >>= 1) { if (t < k) { smA[t] += smA[t + k]; smB[t] += smB[t + k]; } __syncthreads(); }
    if (t == 0) {
        float fr = (float)rep / (float)Pv;
        float mu = smA[0] * fr;
        float var = smB[0] * fr - mu * mu;
        float a = rsqrtf(var + EPS) * lda(g, c, F32);
        alpha[c] = a; beta[c] = lda(bb, c, F32) - mu * a;
    }
    __syncthreads();
}

__device__ __forceinline__ void fold_dev(const void* Wsrc, const void* bias,
                                         const float* alpha, const float* beta,
                                         float* Wf, float* Bf, int Ci, int Co, int omajor,
                                         int j, int t, float* sm, bool F32) {
    float acc = 0.f;
    for (int c = t; c < Ci; c += NTHR) {
        float w = lda(Wsrc, omajor ? (long)j * Ci + c : (long)c * Co + j, F32);
        Wf[(long)c * Co + j] = w * alpha[c];
        acc += w * beta[c];
    }
    sm[t] = acc; __syncthreads();
    for (int k = 128; k > 0; k >>= 1) { if (t < k) sm[t] += sm[t + k]; __syncthreads(); }
    if (t == 0) Bf[j] = lda(bias, j, F32) + sm[0];
    __syncthreads();
}

__device__ __forceinline__ void attn_dev(const float* th, const float* outm, const int* nbr,
                                         float* dst, int co, int Nn, int gtid) {
    int lane = gtid & 63;
    int wv = gtid >> 6;
    const int nw = GSZ >> 6;
    for (int n = wv; n < Nn; n += nw) {
        float r0 = th[(long)n * 128 + lane];
        float r1 = th[(long)n * 128 + 64 + lane];
        int mk[KNB]; float av[KNB];
#pragma unroll
        for (int k = 0; k < KNB; k++) {
            int m = nbr[n * KNB + k]; mk[k] = m;
            float v = r0 * th[(long)m * 128 + lane] + r1 * th[(long)m * 128 + 64 + lane];
#pragma unroll
            for (int off = 32; off > 0; off >>= 1) v += __shfl_xor(v, off, 64);
            av[k] = 1.f / (1.f + expf(-v));
        }
        float amax = av[0];
#pragma unroll
        for (int k = 1; k < KNB; k++) amax = fmaxf(amax, av[k]);
        float den = 0.f;
#pragma unroll
        for (int k = 0; k < KNB; k++) { av[k] = expf(av[k] - amax); den += av[k]; }
        float rden = 1.f / den;
        if (lane < co) {
            float acc = 0.f;
#pragma unroll
            for (int k = 0; k < KNB; k++) acc += av[k] * outm[(long)mk[k] * co + lane];
            dst[(long)n * co + lane] = leaky(acc * rden);
        }
    }
}

__device__ __forceinline__ void dw_dev(const float* In, const void* wsrc, const void* bsrc,
                                       float* Out, int gtid, bool F32) {
    int o = gtid & 127;   // constant across grid-stride since GSZ % 128 == 0
    float wr[25];
#pragma unroll
    for (int i = 0; i < 25; i++) wr[i] = lda(wsrc, (long)o * 25 + i, F32);
    float bias = lda(bsrc, (long)o, F32);
    for (long e = gtid; e < (long)N0 * 128; e += GSZ) {
        int pp = (int)(e >> 7);
        int h = pp >> 7, w = pp & 127;
        float acc = bias;
#pragma unroll
        for (int dh = -2; dh <= 2; dh++) {
            int hh = h + dh;
            if ((unsigned)hh >= (unsigned)H_IMG) continue;
#pragma unroll
            for (int dv = -2; dv <= 2; dv++) {
                int ww = w + dv;
                if ((unsigned)ww >= (unsigned)W_IMG) continue;
                acc += In[(long)(((hh << 7) + ww) << 7) + o] * wr[(dh + 2) * 5 + (dv + 2)];
            }
        }
        Out[e] = leaky(acc);
    }
}

__global__ __launch_bounds__(NTHR) void higcn_fused(Params p) {
    cg::grid_group grid = cg::this_grid();
    const int t = threadIdx.x, b = blockIdx.x;
    const int gtid = b * NTHR + t;
    __shared__ float sA[NTHR], sB[NTHR];

    float* W = p.W;
    int*   dflag = (int*)W;
    float* AB_a = W + 256;
    float* AB_b = W + 512;
    float* WF1  = W + 1024;            // up to 200*128
    float* BF1  = W + 33792;           // 128
    float* WF2  = W + 34048;           // up to 128*64
    float* BF2  = W + 42240;           // 64
    float* R0   = W + 65536;           // 16384*128 (head-gemm out / T1)
    float* R1   = R0 + (long)N0*128;   // 16384*128 (H0=enc0 / F)
    float* H1   = R1 + (long)N0*128;   // 4096*128
    float* TH   = H1 + (long)N1*128;   // 4096*128
    float* OU   = TH + (long)N1*128;   // 4096*64
    float* E1   = OU + (long)N1*64;    // 4096*64 (enc1)
    float* H2   = E1 + (long)N1*64;    // 1024*64
    float* HD   = H2 + (long)N2*64;    // 1024*32
    float* HDE  = HD + (long)N2*32;    // 4096*64

    // ---- S0: dtype detect (block 0) ----
    if (b == 0) {
        const unsigned short* u = (const unsigned short*)p.x;
        int cnt = 0;
        for (int i = t; i < 4096; i += NTHR) { unsigned e = (u[i] >> 7) & 0xFF; cnt += (e >= 0xC0); }
        sA[t] = (float)cnt; __syncthreads();
        for (int k = 128; k > 0; k >>= 1) { if (t < k) sA[t] += sA[t + k]; __syncthreads(); }
        if (t == 0) { dflag[0] = (sA[0] > 32.f) ? 1 : 0; __threadfence(); }
    }
    grid.sync();
    const bool F32 = (dflag[0] != 0);

    // ---- S1: BN stats over raw x (200 channels) ----
    if (b < C_IN) {
        float s = 0.f, s2 = 0.f;
        if (F32) {
            const float* X = (const float*)p.x;
            for (int r = t; r < N0; r += NTHR) { float v = X[(long)r * C_IN + b]; s += v; s2 += v * v; }
        } else {
            const bf16* X = (const bf16*)p.x;
            for (int r = t; r < N0; r += NTHR) { float v = __bfloat162float(X[(long)r * C_IN + b]); s += v; s2 += v * v; }
        }
        sA[t] = s; sB[t] = s2; __syncthreads();
        for (int k = 128; k > 0; k >>= 1) { if (t < k) { sA[t] += sA[t + k]; sB[t] += sB[t + k]; } __syncthreads(); }
        if (t == 0) {
            float mu = sA[0] / (float)N0;
            float var = sB[0] / (float)N0 - mu * mu;
            float a = rsqrtf(var + EPS) * lda(p.hg, b, F32);
            AB_a[b] = a; AB_b[b] = lda(p.hb, b, F32) - mu * a;
        }
    }
    grid.sync();

    // ---- S2: fold head pointwise (omajor) ----
    if (b < 128) fold_dev(p.hpw, p.hpb, AB_a, AB_b, WF1, BF1, C_IN, 128, 1, b, t, sA, F32);
    grid.sync();

    // ---- S3: head GEMM 16384x200 -> 128, leaky -> R0 ----
    if (F32) {
        const float* X = (const float*)p.x;
        for (long i = gtid; i < (long)N0 * 128; i += GSZ) {
            int n = (int)(i >> 7), j = (int)(i & 127);
            const float* in = X + (long)n * C_IN;
            float acc = BF1[j];
#pragma unroll 4
            for (int c = 0; c < C_IN; c++) acc += in[c] * WF1[(long)c * 128 + j];
            R0[i] = leaky(acc);
        }
    } else {
        const bf16* X = (const bf16*)p.x;
        for (long i = gtid; i < (long)N0 * 128; i += GSZ) {
            int n = (int)(i >> 7), j = (int)(i & 127);
            const bf16* in = X + (long)n * C_IN;
            float acc = BF1[j];
#pragma unroll 4
            for (int c = 0; c < C_IN; c++) acc += __bfloat162float(in[c]) * WF1[(long)c * 128 + j];
            R0[i] = leaky(acc);
        }
    }
    grid.sync();

    // ---- S4: head depthwise 5x5 -> R1 (= H0 = enc0) ----
    dw_dev(R0, p.hdw, p.hdb, R1, gtid, F32);
    grid.sync();

    // ---- S5: pool4 H0 -> H1 (4096 x 128) ----
    for (long i = gtid; i < (long)N1 * 128; i += GSZ) {
        int n = (int)(i >> 7), f = (int)(i & 127);
        const float* base = R1 + (long)(4 * n) * 128 + f;
        H1[i] = 0.25f * (base[0] + base[128] + base[256] + base[384]);
    }
    grid.sync();

    // ---- S6: BN stats H1 (128 ch) ----
    if (b < 128) stats_dev(H1, 128, b, N1, 1, N1, p.e0_g, p.e0_b, AB_a, AB_b, b, t, sA, sB, F32);
    grid.sync();

    // ---- S7: fold e0 wt + wo ----
    if (b < 128) fold_dev(p.e0_wt, p.e0_bt, AB_a, AB_b, WF1, BF1, 128, 128, 0, b, t, sA, F32);
    else if (b < 192) fold_dev(p.e0_wo, p.e0_bo, AB_a, AB_b, WF2, BF2, 128, 64, 0, b - 128, t, sA, F32);
    grid.sync();

    // ---- S8: e0 GEMMs: th (4096x128), out (4096x64) ----
    for (long i = gtid; i < (long)N1 * 128; i += GSZ) {
        int n = (int)(i >> 7), j = (int)(i & 127);
        const float* in = H1 + (long)n * 128;
        float acc = BF1[j];
#pragma unroll 4
        for (int c = 0; c < 128; c++) acc += in[c] * WF1[(long)c * 128 + j];
        TH[i] = acc;
    }
    for (long i = gtid; i < (long)N1 * 64; i += GSZ) {
        int n = (int)(i >> 6), j = (int)(i & 63);
        const float* in = H1 + (long)n * 128;
        float acc = BF2[j];
#pragma unroll 4
        for (int c = 0; c < 128; c++) acc += in[c] * WF2[(long)c * 64 + j];
        OU[i] = acc;
    }
    grid.sync();

    // ---- S9: attn e0 -> E1 (enc1) ----
    attn_dev(TH, OU, p.nbr_a, E1, 64, N1, gtid);
    grid.sync();

    // ---- S10: pool4 E1 -> H2 (1024 x 64) ----
    for (long i = gtid; i < (long)N2 * 64; i += GSZ) {
        int n = (int)(i >> 6), f = (int)(i & 63);
        const float* base = E1 + (long)(4 * n) * 64 + f;
        H2[i] = 0.25f * (base[0] + base[64] + base[128] + base[192]);
    }
    grid.sync();

    // ---- S11: BN stats H2 (64 ch) ----
    if (b < 64) stats_dev(H2, 64, b, N2, 1, N2, p.e1_g, p.e1_b, AB_a, AB_b, b, t, sA, sB, F32);
    grid.sync();

    // ---- S12: fold e1 wt + wo ----
    if (b < 128) fold_dev(p.e1_wt, p.e1_bt, AB_a, AB_b, WF1, BF1, 64, 128, 0, b, t, sA, F32);
    else if (b < 160) fold_dev(p.e1_wo, p.e1_bo, AB_a, AB_b, WF2, BF2, 64, 32, 0, b - 128, t, sA, F32);
    grid.sync();

    // ---- S13: e1 GEMMs: th (1024x128), out (1024x32) ----
    for (long i = gtid; i < (long)N2 * 128; i += GSZ) {
        int n = (int)(i >> 7), j = (int)(i & 127);
        const float* in = H2 + (long)n * 64;
        float acc = BF1[j];
#pragma unroll 4
        for (int c = 0; c < 64; c++) acc += in[c] * WF1[(long)c * 128 + j];
        TH[i] = acc;
    }
    for (long i = gtid; i < (long)N2 * 32; i += GSZ) {
        int n = (int)(i >> 5), j = (int)(i & 31);
        const float* in = H2 + (long)n * 64;
        float acc = BF2[j];
#pragma unroll 4
        for (int c = 0; c < 64; c++) acc += in[c] * WF2[(long)c * 32 + j];
        OU[i] = acc;
    }
    grid.sync();

    // ---- S14: attn e1 -> HD (1024 x 32) ----
    attn_dev(TH, OU, p.nbr_b, HD, 32, N2, gtid);
    grid.sync();

    // ---- S15: BN stats for virtual concat [S1@HD (rep4), E1] (96 ch over 4096 rows) ----
    if (b < 32) stats_dev(HD, 32, b, N2, 4, N1, p.d0_g, p.d0_b, AB_a, AB_b, b, t, sA, sB, F32);
    else if (b < 96) stats_dev(E1, 64, b - 32, N1, 1, N1, p.d0_g, p.d0_b, AB_a, AB_b, b, t, sA, sB, F32);
    grid.sync();

    // ---- S16: fold d0 wt + wo ----
    if (b < 128) fold_dev(p.d0_wt, p.d0_bt, AB_a, AB_b, WF1, BF1, 96, 128, 0, b, t, sA, F32);
    else if (b < 192) fold_dev(p.d0_wo, p.d0_bo, AB_a, AB_b, WF2, BF2, 96, 64, 0, b - 128, t, sA, F32);
    grid.sync();

    // ---- S17: d0 GEMMs over virtual concat: th (4096x128), out (4096x64) ----
    for (long i = gtid; i < (long)N1 * 128; i += GSZ) {
        int n = (int)(i >> 7), j = (int)(i & 127);
        const float* hd = HD + (long)(n >> 2) * 32;
        const float* e1 = E1 + (long)n * 64;
        float acc = BF1[j];
#pragma unroll
        for (int c = 0; c < 32; c++) acc += hd[c] * WF1[(long)c * 128 + j];
#pragma unroll 4
        for (int c = 0; c < 64; c++) acc += e1[c] * WF1[(long)(c + 32) * 128 + j];
        TH[i] = acc;
    }
    for (long i = gtid; i < (long)N1 * 64; i += GSZ) {
        int n = (int)(i >> 6), j = (int)(i & 63);
        const float* hd = HD + (long)(n >> 2) * 32;
        const float* e1 = E1 + (long)n * 64;
        float acc = BF2[j];
#pragma unroll
        for (int c = 0; c < 32; c++) acc += hd[c] * WF2[(long)c * 64 + j];
#pragma unroll 4
        for (int c = 0; c < 64; c++) acc += e1[c] * WF2[(long)(c + 32) * 64 + j];
        OU[i] = acc;
    }
    grid.sync();

    // ---- S18: attn d0 -> HDE (4096 x 64) ----
    attn_dev(TH, OU, p.nbr_a, HDE, 64, N1, gtid);
    grid.sync();

    // ---- S19: BN stats for virtual concat [S0@HDE (rep4), H0] (192 ch over 16384 rows) ----
    if (b < 64) stats_dev(HDE, 64, b, N1, 4, N0, p.tg, p.tb, AB_a, AB_b, b, t, sA, sB, F32);
    else if (b < 192) stats_dev(R1, 128, b - 64, N0, 1, N0, p.tg, p.tb, AB_a, AB_b, b, t, sA, sB, F32);
    grid.sync();

    // ---- S20: fold tail pointwise (omajor, 192 -> 128) ----
    if (b < 128) fold_dev(p.tpw, p.tpb, AB_a, AB_b, WF1, BF1, 192, 128, 1, b, t, sA, F32);
    grid.sync();

    // ---- S21: tail GEMM over virtual concat (16384 x 192 -> 128), leaky -> R0 (T1) ----
    for (long i = gtid; i < (long)N0 * 128; i += GSZ) {
        int n = (int)(i >> 7), j = (int)(i & 127);
        const float* hd = HDE + (long)(n >> 2) * 64;
        const float* h0 = R1 + (long)n * 128;
        float acc = BF1[j];
#pragma unroll 4
        for (int c = 0; c < 64; c++) acc += hd[c] * WF1[(long)c * 128 + j];
#pragma unroll 4
        for (int c = 0; c < 128; c++) acc += h0[c] * WF1[(long)(c + 64) * 128 + j];
        R0[i] = leaky(acc);
    }
    grid.sync();

    // ---- S22: tail depthwise 5x5 -> R1 (F; H0 is dead now) ----
    dw_dev(R0, p.tdw, p.tdb, R1, gtid, F32);
    grid.sync();

    // ---- S23: classifier + softmax(16) ----
    for (long i = gtid; i < (long)N0 * NCLS; i += GSZ) {
        int pp = (int)(i >> 4), j = (int)(i & 15);
        const float* Fv = R1 + (long)pp * 128;
        float acc;
        if (F32) {
            const float* wsw = (const float*)p.wsw;
            acc = ((const float*)p.wb)[j];
#pragma unroll 4
            for (int c = 0; c < 128; c++) acc += Fv[c] * wsw[c * 16 + j];
        } else {
            const bf16* wsw = (const bf16*)p.wsw;
            acc = __bfloat162float(((const bf16*)p.wb)[j]);
#pragma unroll 4
            for (int c = 0; c < 128; c++) acc += Fv[c] * __bfloat162float(wsw[c * 16 + j]);
        }
        float m = acc;
#pragma unroll
        for (int s = 8; s > 0; s >>= 1) m = fmaxf(m, __shfl_xor(m, s, 16));
        float e = expf(acc - m);
        float d = e;
#pragma unroll
        for (int s = 8; s > 0; s >>= 1) d += __shfl_xor(d, s, 16);
        float r = e / d;
        if (F32) ((float*)p.out)[i] = r;
        else ((bf16*)p.out)[i] = __float2bfloat16(r);
    }
}

// ================= host side =================
extern "C" void kernel_launch(void* const* d_in, const int* in_sizes, int n_in,
                              void* d_out, int out_size, void* d_ws, size_t ws_size,
                              hipStream_t stream) {
    bool dict = (in_sizes[1] > 1000000);
    int I_x, I_nbr_a, I_nbr_b, I_hg, I_ws, I_e0, I_e1, I_d0, I_tg;
    if (dict) {
        I_x = 0; I_nbr_a = 5; I_nbr_b = 6; I_hg = 7; I_e0 = 13; I_e1 = 19; I_d0 = 25; I_tg = 31; I_ws = 37;
    } else {
        I_x = 0; I_hg = 1; I_e0 = 7; I_e1 = 13; I_d0 = 19; I_tg = 25; I_ws = 31; I_nbr_a = 37; I_nbr_b = 38;
    }
    Params prm;
    prm.x = d_in[I_x];
    prm.nbr_a = (const int*)d_in[I_nbr_a];
    prm.nbr_b = (const int*)d_in[I_nbr_b];
    prm.hg = d_in[I_hg + 0]; prm.hb = d_in[I_hg + 1]; prm.hpw = d_in[I_hg + 2];
    prm.hpb = d_in[I_hg + 3]; prm.hdw = d_in[I_hg + 4]; prm.hdb = d_in[I_hg + 5];
    prm.e0_g = d_in[I_e0 + 0]; prm.e0_b = d_in[I_e0 + 1]; prm.e0_wt = d_in[I_e0 + 2];
    prm.e0_bt = d_in[I_e0 + 3]; prm.e0_wo = d_in[I_e0 + 4]; prm.e0_bo = d_in[I_e0 + 5];
    prm.e1_g = d_in[I_e1 + 0]; prm.e1_b = d_in[I_e1 + 1]; prm.e1_wt = d_in[I_e1 + 2];
    prm.e1_bt = d_in[I_e1 + 3]; prm.e1_wo = d_in[I_e1 + 4]; prm.e1_bo = d_in[I_e1 + 5];
    prm.d0_g = d_in[I_d0 + 0]; prm.d0_b = d_in[I_d0 + 1]; prm.d0_wt = d_in[I_d0 + 2];
    prm.d0_bt = d_in[I_d0 + 3]; prm.d0_wo = d_in[I_d0 + 4]; prm.d0_bo = d_in[I_d0 + 5];
    prm.tg = d_in[I_tg + 0]; prm.tb = d_in[I_tg + 1]; prm.tpw = d_in[I_tg + 2];
    prm.tpb = d_in[I_tg + 3]; prm.tdw = d_in[I_tg + 4]; prm.tdb = d_in[I_tg + 5];
    prm.wsw = d_in[I_ws + 0]; prm.wb = d_in[I_ws + 1];
    prm.out = d_out;
    prm.W = (float*)d_ws;

    void* args[] = { (void*)&prm };
    hipLaunchCooperativeKernel((const void*)higcn_fused, dim3(NBLK), dim3(NTHR), args, 0, stream);
}

// Round 4
// 1534.624 us; speedup vs baseline: 1.5700x; 1.5700x over previous
//
#include <hip/hip_runtime.h>
#include <hip/hip_bf16.h>
#include <math.h>

using bf16 = __hip_bfloat16;

#define H_IMG 128
#define W_IMG 128
#define C_IN  200
#define NCLS  16
#define N0    16384
#define N1    4096
#define N2    1024
#define KNB   16
#define EPS   1e-5f
#define SLOPE 0.01f

#define NBLK  512
#define NTHR  256
#define GSZ   (NBLK * NTHR)   // 131072 threads, 2048 waves

__device__ __forceinline__ float leaky(float v) { return v >= 0.f ? v : SLOPE * v; }
__device__ __forceinline__ float cv(float v) { return v; }
__device__ __forceinline__ float cv(bf16 v) { return __bfloat162float(v); }
__device__ __forceinline__ void stv(float* p, long i, float v) { p[i] = v; }
__device__ __forceinline__ void stv(bf16* p, long i, float v) { p[i] = __float2bfloat16(v); }
__device__ __forceinline__ void atomAdd(float* p, float v) { unsafeAtomicAdd(p, v); }

struct Params {
    const void *x; const int *nbr_a, *nbr_b;
    const void *hg,*hb,*hpw,*hpb,*hdw,*hdb;
    const void *e0_g,*e0_b,*e0_wt,*e0_bt,*e0_wo,*e0_bo;
    const void *e1_g,*e1_b,*e1_wt,*e1_bt,*e1_wo,*e1_bo;
    const void *d0_g,*d0_b,*d0_wt,*d0_bt,*d0_wo,*d0_bo;
    const void *tg,*tb,*tpw,*tpb,*tdw,*tdb,*wsw,*wb;
    void* out; float* W;
};

// ---------------- fast grid barrier (custom; ockl's is ~80us) ----------------
__device__ __forceinline__ void gbar(int* cnt, int* rel, int gen) {
    __syncthreads();
    if (threadIdx.x == 0) {
        __threadfence();   // release: drain + L2 writeback so other XCDs see our stage output
        int prev = __hip_atomic_fetch_add(cnt, 1, __ATOMIC_RELAXED, __HIP_MEMORY_SCOPE_AGENT);
        if (prev == NBLK - 1) {
            __hip_atomic_store(cnt, 0, __ATOMIC_RELAXED, __HIP_MEMORY_SCOPE_AGENT);
            __hip_atomic_store(rel, gen, __ATOMIC_RELEASE, __HIP_MEMORY_SCOPE_AGENT);
        } else {
            while (__hip_atomic_load(rel, __ATOMIC_RELAXED, __HIP_MEMORY_SCOPE_AGENT) < gen) {
                __builtin_amdgcn_s_sleep(2);
            }
        }
        __threadfence();   // acquire: invalidate caches before reading peers' output
    }
    __syncthreads();
}

// ---------------- derive alpha/beta from sums into LDS ----------------
template <typename T>
__device__ __forceinline__ void derive_ab(const float* gs, const float* gq, const T* g, const T* bb,
                                          int C, float invP, float rep, float* la, float* lb, int t) {
    if (t < C) {
        float mu = gs[t] * rep * invP;
        float var = gq[t] * rep * invP - mu * mu;
        float a = rsqrtf(var + EPS) * cv(g[t]);
        la[t] = a; lb[t] = cv(bb[t]) - mu * a;
    }
    __syncthreads();
}

// ---------------- stage A: stats over x + weight transposes ----------------
template <typename T>
__device__ void statsX(const T* x, float* gs, float* gq, int b, int t) {
    if (t < C_IN) {
        float s = 0.f, q = 0.f;
        int r0 = b * (N0 / NBLK);
        for (int r = 0; r < N0 / NBLK; r++) {
            float v = cv(x[(long)(r0 + r) * C_IN + t]);
            s += v; q += v * v;
        }
        atomAdd(&gs[t], s); atomAdd(&gq[t], q);
    }
}

template <typename T>
__device__ void transp(const T* src, float* dst, int CI, int gtid) { // src [128][CI] -> dst [CI][128]
    for (int i = gtid; i < CI * 128; i += GSZ) {
        int j = i & 127, c = i >> 7;
        dst[i] = cv(src[j * CI + c]);
    }
}

// ---------------- stage B: head GEMM (BN inline), 2-col tile ----------------
template <typename T>
__device__ void head_gemm(const T* x, const float* Wt, const T* bias, float* Out,
                          const float* la, const float* lb, int gtid) {
    for (long i = gtid; i < (long)N0 * 64; i += GSZ) {
        int n = (int)(i >> 6), j0 = (int)(i & 63);
        const T* in = x + (long)n * C_IN;
        float a0 = cv(bias[j0]), a1 = cv(bias[j0 + 64]);
#pragma unroll 4
        for (int c = 0; c < C_IN; c++) {
            float v = fmaf(cv(in[c]), la[c], lb[c]);
            a0 = fmaf(v, Wt[c * 128 + j0], a0);
            a1 = fmaf(v, Wt[c * 128 + j0 + 64], a1);
        }
        Out[(long)n * 128 + j0] = leaky(a0);
        Out[(long)n * 128 + j0 + 64] = leaky(a1);
    }
}

// ---------------- stage C: head dw 5x5 + pool4 + fused stats (H1, enc0) ----------------
template <typename T>
__device__ void dw_head(const float* In, const T* dwp, const T* dbp, float* R1, float* H1,
                        float* gsH, float* gqH, float* gsR, float* gqR,
                        int gtid, int t, float* sm1, float* sm2) {
    const int o = gtid & 127;
    float wr[25];
#pragma unroll
    for (int i = 0; i < 25; i++) wr[i] = cv(dwp[o * 25 + i]);
    float bias = cv(dbp[o]);
    float sH = 0.f, qH = 0.f, sR = 0.f, qR = 0.f;
    for (long e = gtid; e < (long)(N0 / 4) * 128; e += GSZ) {
        int n = (int)(e >> 7);
        int pp0 = n << 2;
        int h = pp0 >> 7, w0 = pp0 & 127;
        float pooled = 0.f;
#pragma unroll
        for (int k = 0; k < 4; k++) {
            int w = w0 + k;
            float acc = bias;
#pragma unroll
            for (int dh = -2; dh <= 2; dh++) {
                int hh = h + dh;
                if ((unsigned)hh >= 128u) continue;
#pragma unroll
                for (int dv = -2; dv <= 2; dv++) {
                    int ww = w + dv;
                    if ((unsigned)ww >= 128u) continue;
                    acc = fmaf(In[(long)(((hh << 7) + ww) << 7) + o], wr[(dh + 2) * 5 + (dv + 2)], acc);
                }
            }
            float lk = leaky(acc);
            R1[(long)(pp0 + k) * 128 + o] = lk;
            sR += lk; qR += lk * lk; pooled += lk;
        }
        pooled *= 0.25f;
        H1[(long)n * 128 + o] = pooled;
        sH += pooled; qH += pooled * pooled;
    }
    sm1[t] = sH; sm2[t] = qH; __syncthreads();
    if (t < 128) { atomAdd(&gsH[t], sm1[t] + sm1[t + 128]); atomAdd(&gqH[t], sm2[t] + sm2[t + 128]); }
    __syncthreads();
    sm1[t] = sR; sm2[t] = qR; __syncthreads();
    if (t < 128) { atomAdd(&gsR[t], sm1[t] + sm1[t + 128]); atomAdd(&gqR[t], sm2[t] + sm2[t + 128]); }
    __syncthreads();
}

// ---------------- generic 2-col GEMM with inline BN ----------------
template <typename TW, int CI, int CO>
__device__ void std_gemm(const float* In, const TW* w, const TW* bias, float* Out,
                         const float* la, const float* lb, int N, int gtid) {
    const int HALF = CO / 2;
    for (long i = gtid; i < (long)N * HALF; i += GSZ) {
        int n = (int)(i / HALF);
        int j0 = (int)(i - (long)n * HALF);
        const float* in = In + (long)n * CI;
        float a0 = cv(bias[j0]), a1 = cv(bias[j0 + HALF]);
#pragma unroll 4
        for (int c = 0; c < CI; c++) {
            float v = fmaf(in[c], la[c], lb[c]);
            a0 = fmaf(v, cv(w[(long)c * CO + j0]), a0);
            a1 = fmaf(v, cv(w[(long)c * CO + j0 + HALF]), a1);
        }
        Out[(long)n * CO + j0] = a0;
        Out[(long)n * CO + j0 + HALF] = a1;
    }
}

// ---------------- concat-input 2-col GEMM (A indexed n>>2 width C1; B indexed n width C2) ----------------
template <typename TW, typename TB, int C1, int C2, int CO, bool ACT>
__device__ void cat_gemm(const float* A, const float* B, const TW* w, const TB* bias, float* Out,
                         const float* la, const float* lb, int N, int gtid) {
    const int HALF = CO / 2;
    for (long i = gtid; i < (long)N * HALF; i += GSZ) {
        int n = (int)(i / HALF);
        int j0 = (int)(i - (long)n * HALF);
        const float* a = A + (long)(n >> 2) * C1;
        const float* bb = B + (long)n * C2;
        float a0 = cv(bias[j0]), a1 = cv(bias[j0 + HALF]);
#pragma unroll 4
        for (int c = 0; c < C1; c++) {
            float v = fmaf(a[c], la[c], lb[c]);
            a0 = fmaf(v, cv(w[(long)c * CO + j0]), a0);
            a1 = fmaf(v, cv(w[(long)c * CO + j0 + HALF]), a1);
        }
#pragma unroll 4
        for (int c = 0; c < C2; c++) {
            float v = fmaf(bb[c], la[C1 + c], lb[C1 + c]);
            a0 = fmaf(v, cv(w[(long)(C1 + c) * CO + j0]), a0);
            a1 = fmaf(v, cv(w[(long)(C1 + c) * CO + j0 + HALF]), a1);
        }
        if (ACT) { a0 = leaky(a0); a1 = leaky(a1); }
        Out[(long)n * CO + j0] = a0;
        Out[(long)n * CO + j0 + HALF] = a1;
    }
}

// ---------------- attention node (one wave = one node) ----------------
template <int CO>
__device__ __forceinline__ float attn_node(const float* th, const float* ou, const int* nbr, int n, int lane) {
    float r0 = th[(long)n * 128 + lane];
    float r1 = th[(long)n * 128 + 64 + lane];
    int mk[KNB]; float av[KNB];
#pragma unroll
    for (int k = 0; k < KNB; k++) {
        int m = nbr[n * KNB + k]; mk[k] = m;
        float v = fmaf(r0, th[(long)m * 128 + lane], r1 * th[(long)m * 128 + 64 + lane]);
#pragma unroll
        for (int off = 32; off > 0; off >>= 1) v += __shfl_xor(v, off, 64);
        av[k] = 1.f / (1.f + expf(-v));
    }
    float amax = av[0];
#pragma unroll
    for (int k = 1; k < KNB; k++) amax = fmaxf(amax, av[k]);
    float den = 0.f;
#pragma unroll
    for (int k = 0; k < KNB; k++) { av[k] = expf(av[k] - amax); den += av[k]; }
    float acc = 0.f;
    if (lane < CO) {
#pragma unroll
        for (int k = 0; k < KNB; k++) acc = fmaf(av[k], ou[(long)mk[k] * CO + lane], acc);
    }
    return leaky(acc / den);
}

__device__ void attn_e0(const float* TH_, const float* OU_, const int* nbr, float* E1, float* H2,
                        float* gsH2, float* gqH2, float* gsE, float* gqE, int gtid) {
    int lane = gtid & 63, wv = gtid >> 6;
    if (wv < N1 / 4) {
        float sE = 0.f, qE = 0.f, pooled = 0.f;
#pragma unroll
        for (int k = 0; k < 4; k++) {
            int n = (wv << 2) + k;
            float v = attn_node<64>(TH_, OU_, nbr, n, lane);
            E1[(long)n * 64 + lane] = v;
            sE += v; qE += v * v; pooled += v;
        }
        pooled *= 0.25f;
        H2[(long)wv * 64 + lane] = pooled;
        atomAdd(&gsE[lane], sE); atomAdd(&gqE[lane], qE);
        atomAdd(&gsH2[lane], pooled); atomAdd(&gqH2[lane], pooled * pooled);
    }
}

__device__ void attn_e1(const float* TH_, const float* OU_, const int* nbr, float* HD,
                        float* gs, float* gq, int gtid) {
    int lane = gtid & 63, wv = gtid >> 6;
    if (wv < N2) {
        float v = attn_node<32>(TH_, OU_, nbr, wv, lane);
        if (lane < 32) {
            HD[(long)wv * 32 + lane] = v;
            atomAdd(&gs[lane], v); atomAdd(&gq[lane], v * v);
        }
    }
}

__device__ void attn_d0(const float* TH_, const float* OU_, const int* nbr, float* HDE,
                        float* gs, float* gq, int gtid) {
    int lane = gtid & 63, wv = gtid >> 6;
    float s = 0.f, q = 0.f;
    for (int n = wv; n < N1; n += GSZ / 64) {
        float v = attn_node<64>(TH_, OU_, nbr, n, lane);
        HDE[(long)n * 64 + lane] = v;
        s += v; q += v * v;
    }
    atomAdd(&gs[lane], s); atomAdd(&gq[lane], q);
}

// ---------------- stage O': tail dw + classifier fused via LDS ----------------
template <typename T>
__device__ void dw_cls(const float* In, const T* dwp, const T* dbp, const T* wsw, const T* wb,
                       T* out, int b, int t, float* sm1) {
    const int o = t & 127;
    float wr[25];
#pragma unroll
    for (int i = 0; i < 25; i++) wr[i] = cv(dwp[o * 25 + i]);
    float bias = cv(dbp[o]);
    for (int it = 0; it < (N0 * 128) / GSZ; it++) {  // 16
        long ebase = (long)it * GSZ + (long)b * NTHR;
        int p = (int)((ebase + t) >> 7);
        int h = p >> 7, w = p & 127;
        float acc = bias;
#pragma unroll
        for (int dh = -2; dh <= 2; dh++) {
            int hh = h + dh;
            if ((unsigned)hh >= 128u) continue;
#pragma unroll
            for (int dv = -2; dv <= 2; dv++) {
                int ww = w + dv;
                if ((unsigned)ww >= 128u) continue;
                acc = fmaf(In[(long)(((hh << 7) + ww) << 7) + o], wr[(dh + 2) * 5 + (dv + 2)], acc);
            }
        }
        sm1[t] = leaky(acc);
        __syncthreads();
        if (t < 32) {
            int r = t >> 4, j = t & 15;
            const float* Fv = sm1 + r * 128;
            float lg = cv(wb[j]);
#pragma unroll 4
            for (int c = 0; c < 128; c++) lg = fmaf(Fv[c], cv(wsw[c * 16 + j]), lg);
            float m = lg;
#pragma unroll
            for (int s = 8; s > 0; s >>= 1) m = fmaxf(m, __shfl_xor(m, s, 16));
            float ex = expf(lg - m);
            float d = ex;
#pragma unroll
            for (int s = 8; s > 0; s >>= 1) d += __shfl_xor(d, s, 16);
            int p0 = (int)(ebase >> 7);
            stv(out, (long)(p0 + r) * 16 + j, ex / d);
        }
        __syncthreads();
    }
}

// ================= main cooperative kernel =================
__global__ __launch_bounds__(NTHR) void higcn2(Params p) {
    const int t = threadIdx.x, b = blockIdx.x;
    const int gtid = b * NTHR + t;
    __shared__ float sm1[256], sm2[256];

    float* W = p.W;
    int* cnt = (int*)W; int* rel = ((int*)W) + 1;
    float* A0 = W + 16;   float* A1 = W + 272;    // x sums (200)
    float* A2 = W + 528;  float* A3 = W + 784;    // H1 sums (128)
    float* A4 = W + 1040; float* A5 = W + 1296;   // H2 sums (64)
    float* A6 = W + 1552; float* A7 = W + 1808;   // cat1 sums (96: 0..31 HD, 32..95 E1)
    float* A8 = W + 2064; float* A9 = W + 2320;   // cat2 sums (192: 0..63 HDE, 64..191 enc0)
    float* WtH = W + 4096;                        // 200x128
    float* WtT = W + 32768;                       // 192x128
    float* R0  = W + 65536;                       // 16384x128
    float* R1  = R0 + (long)N0 * 128;             // 16384x128 (enc0)
    float* H1  = R1 + (long)N0 * 128;             // 4096x128
    float* TH  = H1 + (long)N1 * 128;             // 4096x128
    float* OU  = TH + (long)N1 * 128;             // 4096x64
    float* E1  = OU + (long)N1 * 64;              // 4096x64
    float* H2  = E1 + (long)N1 * 64;              // 1024x64
    float* HD  = H2 + (long)N2 * 64;              // 1024x32
    float* HDE = HD + (long)N2 * 32;              // 4096x64

    // dtype detect (per-block, no sync needed)
    {
        const unsigned short* u = (const unsigned short*)p.x;
        int cn = 0;
        for (int i = t; i < 4096; i += NTHR) cn += (((u[i] >> 7) & 0xFF) >= 0xC0);
        sm1[t] = (float)cn; __syncthreads();
        for (int k = 128; k > 0; k >>= 1) { if (t < k) sm1[t] += sm1[t + k]; __syncthreads(); }
    }
    const bool F32 = sm1[0] > 32.f;
    __syncthreads();
    int gen = 0;

    // A: stats(x) + transposes
    if (F32) {
        statsX((const float*)p.x, A0, A1, b, t);
        transp((const float*)p.hpw, WtH, 200, gtid);
        transp((const float*)p.tpw, WtT, 192, gtid);
    } else {
        statsX((const bf16*)p.x, A0, A1, b, t);
        transp((const bf16*)p.hpw, WtH, 200, gtid);
        transp((const bf16*)p.tpw, WtT, 192, gtid);
    }
    gbar(cnt, rel, ++gen);

    // B: head GEMM
    if (F32) {
        derive_ab(A0, A1, (const float*)p.hg, (const float*)p.hb, 200, 1.f / N0, 1.f, sm1, sm2, t);
        head_gemm((const float*)p.x, WtH, (const float*)p.hpb, R0, sm1, sm2, gtid);
    } else {
        derive_ab(A0, A1, (const bf16*)p.hg, (const bf16*)p.hb, 200, 1.f / N0, 1.f, sm1, sm2, t);
        head_gemm((const bf16*)p.x, WtH, (const bf16*)p.hpb, R0, sm1, sm2, gtid);
    }
    gbar(cnt, rel, ++gen);

    // C: head dw + pool + stats(H1) + stats(enc0 -> cat2[64..191])
    if (F32) dw_head(R0, (const float*)p.hdw, (const float*)p.hdb, R1, H1, A2, A3, A8 + 64, A9 + 64, gtid, t, sm1, sm2);
    else     dw_head(R0, (const bf16*)p.hdw, (const bf16*)p.hdb, R1, H1, A2, A3, A8 + 64, A9 + 64, gtid, t, sm1, sm2);
    gbar(cnt, rel, ++gen);

    // E: e0 GEMMs
    if (F32) {
        derive_ab(A2, A3, (const float*)p.e0_g, (const float*)p.e0_b, 128, 1.f / N1, 1.f, sm1, sm2, t);
        std_gemm<float, 128, 128>(H1, (const float*)p.e0_wt, (const float*)p.e0_bt, TH, sm1, sm2, N1, gtid);
        std_gemm<float, 128, 64>(H1, (const float*)p.e0_wo, (const float*)p.e0_bo, OU, sm1, sm2, N1, gtid);
    } else {
        derive_ab(A2, A3, (const bf16*)p.e0_g, (const bf16*)p.e0_b, 128, 1.f / N1, 1.f, sm1, sm2, t);
        std_gemm<bf16, 128, 128>(H1, (const bf16*)p.e0_wt, (const bf16*)p.e0_bt, TH, sm1, sm2, N1, gtid);
        std_gemm<bf16, 128, 64>(H1, (const bf16*)p.e0_wo, (const bf16*)p.e0_bo, OU, sm1, sm2, N1, gtid);
    }
    gbar(cnt, rel, ++gen);

    // F: attn e0 + pool + stats(H2) + stats(E1 -> cat1[32..95])
    attn_e0(TH, OU, p.nbr_a, E1, H2, A4, A5, A6 + 32, A7 + 32, gtid);
    gbar(cnt, rel, ++gen);

    // H: e1 GEMMs
    if (F32) {
        derive_ab(A4, A5, (const float*)p.e1_g, (const float*)p.e1_b, 64, 1.f / N2, 1.f, sm1, sm2, t);
        std_gemm<float, 64, 128>(H2, (const float*)p.e1_wt, (const float*)p.e1_bt, TH, sm1, sm2, N2, gtid);
        std_gemm<float, 64, 32>(H2, (const float*)p.e1_wo, (const float*)p.e1_bo, OU, sm1, sm2, N2, gtid);
    } else {
        derive_ab(A4, A5, (const bf16*)p.e1_g, (const bf16*)p.e1_b, 64, 1.f / N2, 1.f, sm1, sm2, t);
        std_gemm<bf16, 64, 128>(H2, (const bf16*)p.e1_wt, (const bf16*)p.e1_bt, TH, sm1, sm2, N2, gtid);
        std_gemm<bf16, 64, 32>(H2, (const bf16*)p.e1_wo, (const bf16*)p.e1_bo, OU, sm1, sm2, N2, gtid);
    }
    gbar(cnt, rel, ++gen);

    // I: attn e1 + stats(HD -> cat1[0..31])
    attn_e1(TH, OU, p.nbr_b, HD, A6, A7, gtid);
    gbar(cnt, rel, ++gen);

    // K: d0 GEMMs (virtual concat)
    if (F32) {
        derive_ab(A6, A7, (const float*)p.d0_g, (const float*)p.d0_b, 32, 1.f / N1, 4.f, sm1, sm2, t);
        derive_ab(A6 + 32, A7 + 32, ((const float*)p.d0_g) + 32, ((const float*)p.d0_b) + 32, 64, 1.f / N1, 1.f, sm1 + 32, sm2 + 32, t);
        cat_gemm<float, float, 32, 64, 128, false>(HD, E1, (const float*)p.d0_wt, (const float*)p.d0_bt, TH, sm1, sm2, N1, gtid);
        cat_gemm<float, float, 32, 64, 64, false>(HD, E1, (const float*)p.d0_wo, (const float*)p.d0_bo, OU, sm1, sm2, N1, gtid);
    } else {
        derive_ab(A6, A7, (const bf16*)p.d0_g, (const bf16*)p.d0_b, 32, 1.f / N1, 4.f, sm1, sm2, t);
        derive_ab(A6 + 32, A7 + 32, ((const bf16*)p.d0_g) + 32, ((const bf16*)p.d0_b) + 32, 64, 1.f / N1, 1.f, sm1 + 32, sm2 + 32, t);
        cat_gemm<bf16, bf16, 32, 64, 128, false>(HD, E1, (const bf16*)p.d0_wt, (const bf16*)p.d0_bt, TH, sm1, sm2, N1, gtid);
        cat_gemm<bf16, bf16, 32, 64, 64, false>(HD, E1, (const bf16*)p.d0_wo, (const bf16*)p.d0_bo, OU, sm1, sm2, N1, gtid);
    }
    gbar(cnt, rel, ++gen);

    // L: attn d0 + stats(HDE -> cat2[0..63])
    attn_d0(TH, OU, p.nbr_a, HDE, A8, A9, gtid);
    gbar(cnt, rel, ++gen);

    // N: tail GEMM (virtual concat, transposed weights)
    if (F32) {
        derive_ab(A8, A9, (const float*)p.tg, (const float*)p.tb, 64, 1.f / N0, 4.f, sm1, sm2, t);
        derive_ab(A8 + 64, A9 + 64, ((const float*)p.tg) + 64, ((const float*)p.tb) + 64, 128, 1.f / N0, 1.f, sm1 + 64, sm2 + 64, t);
        cat_gemm<float, float, 64, 128, 128, true>(HDE, R1, WtT, (const float*)p.tpb, R0, sm1, sm2, N0, gtid);
    } else {
        derive_ab(A8, A9, (const bf16*)p.tg, (const bf16*)p.tb, 64, 1.f / N0, 4.f, sm1, sm2, t);
        derive_ab(A8 + 64, A9 + 64, ((const bf16*)p.tg) + 64, ((const bf16*)p.tb) + 64, 128, 1.f / N0, 1.f, sm1 + 64, sm2 + 64, t);
        cat_gemm<float, bf16, 64, 128, 128, true>(HDE, R1, WtT, (const bf16*)p.tpb, R0, sm1, sm2, N0, gtid);
    }
    gbar(cnt, rel, ++gen);

    // O': tail dw + classifier
    if (F32) dw_cls(R0, (const float*)p.tdw, (const float*)p.tdb, (const float*)p.wsw, (const float*)p.wb, (float*)p.out, b, t, sm1);
    else     dw_cls(R0, (const bf16*)p.tdw, (const bf16*)p.tdb, (const bf16*)p.wsw, (const bf16*)p.wb, (bf16*)p.out, b, t, sm1);
}

// ---------------- init: zero barrier + accumulators ----------------
__global__ void init_ws(float* W) {
    int i = blockIdx.x * 256 + threadIdx.x;
    if (i < 4096) W[i] = 0.f;
}

// ================= host side =================
extern "C" void kernel_launch(void* const* d_in, const int* in_sizes, int n_in,
                              void* d_out, int out_size, void* d_ws, size_t ws_size,
                              hipStream_t stream) {
    bool dict = (in_sizes[1] > 1000000);
    int I_x, I_nbr_a, I_nbr_b, I_hg, I_ws, I_e0, I_e1, I_d0, I_tg;
    if (dict) {
        I_x = 0; I_nbr_a = 5; I_nbr_b = 6; I_hg = 7; I_e0 = 13; I_e1 = 19; I_d0 = 25; I_tg = 31; I_ws = 37;
    } else {
        I_x = 0; I_hg = 1; I_e0 = 7; I_e1 = 13; I_d0 = 19; I_tg = 25; I_ws = 31; I_nbr_a = 37; I_nbr_b = 38;
    }
    Params prm;
    prm.x = d_in[I_x];
    prm.nbr_a = (const int*)d_in[I_nbr_a];
    prm.nbr_b = (const int*)d_in[I_nbr_b];
    prm.hg = d_in[I_hg + 0]; prm.hb = d_in[I_hg + 1]; prm.hpw = d_in[I_hg + 2];
    prm.hpb = d_in[I_hg + 3]; prm.hdw = d_in[I_hg + 4]; prm.hdb = d_in[I_hg + 5];
    prm.e0_g = d_in[I_e0 + 0]; prm.e0_b = d_in[I_e0 + 1]; prm.e0_wt = d_in[I_e0 + 2];
    prm.e0_bt = d_in[I_e0 + 3]; prm.e0_wo = d_in[I_e0 + 4]; prm.e0_bo = d_in[I_e0 + 5];
    prm.e1_g = d_in[I_e1 + 0]; prm.e1_b = d_in[I_e1 + 1]; prm.e1_wt = d_in[I_e1 + 2];
    prm.e1_bt = d_in[I_e1 + 3]; prm.e1_wo = d_in[I_e1 + 4]; prm.e1_bo = d_in[I_e1 + 5];
    prm.d0_g = d_in[I_d0 + 0]; prm.d0_b = d_in[I_d0 + 1]; prm.d0_wt = d_in[I_d0 + 2];
    prm.d0_bt = d_in[I_d0 + 3]; prm.d0_wo = d_in[I_d0 + 4]; prm.d0_bo = d_in[I_d0 + 5];
    prm.tg = d_in[I_tg + 0]; prm.tb = d_in[I_tg + 1]; prm.tpw = d_in[I_tg + 2];
    prm.tpb = d_in[I_tg + 3]; prm.tdw = d_in[I_tg + 4]; prm.tdb = d_in[I_tg + 5];
    prm.wsw = d_in[I_ws + 0]; prm.wb = d_in[I_ws + 1];
    prm.out = d_out;
    prm.W = (float*)d_ws;

    init_ws<<<16, 256, 0, stream>>>((float*)d_ws);
    void* args[] = { (void*)&prm };
    hipLaunchCooperativeKernel((const void*)higcn2, dim3(NBLK), dim3(NTHR), args, 0, stream);
}

// Round 5
// 1188.043 us; speedup vs baseline: 2.0280x; 1.2917x over previous
//
#include <hip/hip_runtime.h>
#include <hip/hip_bf16.h>
#include <math.h>

using bf16 = __hip_bfloat16;

#define H_IMG 128
#define W_IMG 128
#define C_IN  200
#define NCLS  16
#define N0    16384
#define N1    4096
#define N2    1024
#define KNB   16
#define EPS   1e-5f
#define SLOPE 0.01f

#define NBLK  256
#define NTHR  512
#define GSZ   (NBLK * NTHR)   // 131072 threads, 2048 waves
#define NGRP  32              // 8 blocks per barrier group

__device__ __forceinline__ float leaky(float v) { return v >= 0.f ? v : SLOPE * v; }
__device__ __forceinline__ float cv(float v) { return v; }
__device__ __forceinline__ float cv(bf16 v) { return __bfloat162float(v); }
__device__ __forceinline__ void stv(float* p, long i, float v) { p[i] = v; }
__device__ __forceinline__ void stv(bf16* p, long i, float v) { p[i] = __float2bfloat16(v); }
__device__ __forceinline__ void atomAdd(float* p, float v) { unsafeAtomicAdd(p, v); }

struct Params {
    const void *x; const int *nbr_a, *nbr_b;
    const void *hg,*hb,*hpw,*hpb,*hdw,*hdb;
    const void *e0_g,*e0_b,*e0_wt,*e0_bt,*e0_wo,*e0_bo;
    const void *e1_g,*e1_b,*e1_wt,*e1_bt,*e1_wo,*e1_bo;
    const void *d0_g,*d0_b,*d0_wt,*d0_bt,*d0_wo,*d0_bo;
    const void *tg,*tb,*tpw,*tpb,*tdw,*tdb,*wsw,*wb;
    void* out; float* W;
};

// ---------------- hierarchical grid barrier (low-contention, no-reset generation counters) ----------------
// int layout in ws: [0]=root, [32]=rel, [64 + g*32]=grp[g]   (128B apart)
__device__ __forceinline__ void gbar(int* ib, int gen) {
    __syncthreads();
    if (threadIdx.x == 0) {
        int g = blockIdx.x >> 3;
        __builtin_amdgcn_fence(__ATOMIC_RELEASE, "agent");  // wb: our stage output -> LLC
        int prev = __hip_atomic_fetch_add(&ib[64 + g * 32], 1, __ATOMIC_RELAXED, __HIP_MEMORY_SCOPE_AGENT);
        if (prev == gen * 8 - 1) {   // last of my 8-block group for this generation
            int r = __hip_atomic_fetch_add(&ib[0], 1, __ATOMIC_RELAXED, __HIP_MEMORY_SCOPE_AGENT);
            if (r == gen * NGRP - 1) // last group overall
                __hip_atomic_store(&ib[32], gen, __ATOMIC_RELAXED, __HIP_MEMORY_SCOPE_AGENT);
        }
        while (__hip_atomic_load(&ib[32], __ATOMIC_RELAXED, __HIP_MEMORY_SCOPE_AGENT) < gen)
            __builtin_amdgcn_s_sleep(1);
        __builtin_amdgcn_fence(__ATOMIC_ACQUIRE, "agent");  // inv: see peers' output
    }
    __syncthreads();
}

// ---------------- derive alpha/beta from sums into LDS ----------------
template <typename T>
__device__ __forceinline__ void derive_ab(const float* gs, const float* gq, const T* g, const T* bb,
                                          int C, float invP, float rep, float* la, float* lb, int t) {
    if (t < C) {
        float mu = gs[t] * rep * invP;
        float var = gq[t] * rep * invP - mu * mu;
        float a = rsqrtf(var + EPS) * cv(g[t]);
        la[t] = a; lb[t] = cv(bb[t]) - mu * a;
    }
    __syncthreads();
}

// ---------------- stage A: stats over x + weight transposes ----------------
template <typename T>
__device__ void statsX(const T* x, float* gs, float* gq, int b, int t) {
    if (t < C_IN) {
        float s = 0.f, q = 0.f;
        int r0 = b * (N0 / NBLK);
        for (int r = 0; r < N0 / NBLK; r++) {
            float v = cv(x[(long)(r0 + r) * C_IN + t]);
            s += v; q += v * v;
        }
        atomAdd(&gs[t], s); atomAdd(&gq[t], q);
    }
}

template <typename T>
__device__ void transp(const T* src, float* dst, int CI, int gtid) { // src [128][CI] -> dst [CI][128]
    for (int i = gtid; i < CI * 128; i += GSZ) {
        int j = i & 127, c = i >> 7;
        dst[i] = cv(src[j * CI + c]);
    }
}

// ---------------- stage B: head GEMM (BN inline), 2-col tile ----------------
template <typename T>
__device__ void head_gemm(const T* x, const float* Wt, const T* bias, float* Out,
                          const float* la, const float* lb, int gtid) {
    for (long i = gtid; i < (long)N0 * 64; i += GSZ) {
        int n = (int)(i >> 6), j0 = (int)(i & 63);
        const T* in = x + (long)n * C_IN;
        float a0 = cv(bias[j0]), a1 = cv(bias[j0 + 64]);
#pragma unroll 4
        for (int c = 0; c < C_IN; c++) {
            float v = fmaf(cv(in[c]), la[c], lb[c]);
            a0 = fmaf(v, Wt[c * 128 + j0], a0);
            a1 = fmaf(v, Wt[c * 128 + j0 + 64], a1);
        }
        Out[(long)n * 128 + j0] = leaky(a0);
        Out[(long)n * 128 + j0 + 64] = leaky(a1);
    }
}

// ---------------- stage C: head dw 5x5 + pool4 + fused stats (H1, enc0) ----------------
template <typename T>
__device__ void dw_head(const float* In, const T* dwp, const T* dbp, float* R1, float* H1,
                        float* gsH, float* gqH, float* gsR, float* gqR,
                        int gtid, int t, float* sm1, float* sm2) {
    const int o = gtid & 127;
    float wr[25];
#pragma unroll
    for (int i = 0; i < 25; i++) wr[i] = cv(dwp[o * 25 + i]);
    float bias = cv(dbp[o]);
    float sH = 0.f, qH = 0.f, sR = 0.f, qR = 0.f;
    for (long e = gtid; e < (long)(N0 / 4) * 128; e += GSZ) {
        int n = (int)(e >> 7);
        int pp0 = n << 2;
        int h = pp0 >> 7, w0 = pp0 & 127;
        float pooled = 0.f;
#pragma unroll
        for (int k = 0; k < 4; k++) {
            int w = w0 + k;
            float acc = bias;
#pragma unroll
            for (int dh = -2; dh <= 2; dh++) {
                int hh = h + dh;
                if ((unsigned)hh >= 128u) continue;
#pragma unroll
                for (int dv = -2; dv <= 2; dv++) {
                    int ww = w + dv;
                    if ((unsigned)ww >= 128u) continue;
                    acc = fmaf(In[(long)(((hh << 7) + ww) << 7) + o], wr[(dh + 2) * 5 + (dv + 2)], acc);
                }
            }
            float lk = leaky(acc);
            R1[(long)(pp0 + k) * 128 + o] = lk;
            sR += lk; qR += lk * lk; pooled += lk;
        }
        pooled *= 0.25f;
        H1[(long)n * 128 + o] = pooled;
        sH += pooled; qH += pooled * pooled;
    }
    sm1[t] = sH; sm2[t] = qH; __syncthreads();
    if (t < 256) { sm1[t] += sm1[t + 256]; sm2[t] += sm2[t + 256]; } __syncthreads();
    if (t < 128) { atomAdd(&gsH[t], sm1[t] + sm1[t + 128]); atomAdd(&gqH[t], sm2[t] + sm2[t + 128]); }
    __syncthreads();
    sm1[t] = sR; sm2[t] = qR; __syncthreads();
    if (t < 256) { sm1[t] += sm1[t + 256]; sm2[t] += sm2[t + 256]; } __syncthreads();
    if (t < 128) { atomAdd(&gsR[t], sm1[t] + sm1[t + 128]); atomAdd(&gqR[t], sm2[t] + sm2[t + 128]); }
    __syncthreads();
}

// ---------------- generic 2-col GEMM with inline BN ----------------
template <typename TW, int CI, int CO>
__device__ void std_gemm(const float* In, const TW* w, const TW* bias, float* Out,
                         const float* la, const float* lb, int N, int gtid) {
    const int HALF = CO / 2;
    for (long i = gtid; i < (long)N * HALF; i += GSZ) {
        int n = (int)(i / HALF);
        int j0 = (int)(i - (long)n * HALF);
        const float* in = In + (long)n * CI;
        float a0 = cv(bias[j0]), a1 = cv(bias[j0 + HALF]);
#pragma unroll 4
        for (int c = 0; c < CI; c++) {
            float v = fmaf(in[c], la[c], lb[c]);
            a0 = fmaf(v, cv(w[(long)c * CO + j0]), a0);
            a1 = fmaf(v, cv(w[(long)c * CO + j0 + HALF]), a1);
        }
        Out[(long)n * CO + j0] = a0;
        Out[(long)n * CO + j0 + HALF] = a1;
    }
}

// ---------------- concat-input 2-col GEMM ----------------
template <typename TW, typename TB, int C1, int C2, int CO, bool ACT>
__device__ void cat_gemm(const float* A, const float* B, const TW* w, const TB* bias, float* Out,
                         const float* la, const float* lb, int N, int gtid) {
    const int HALF = CO / 2;
    for (long i = gtid; i < (long)N * HALF; i += GSZ) {
        int n = (int)(i / HALF);
        int j0 = (int)(i - (long)n * HALF);
        const float* a = A + (long)(n >> 2) * C1;
        const float* bb = B + (long)n * C2;
        float a0 = cv(bias[j0]), a1 = cv(bias[j0 + HALF]);
#pragma unroll 4
        for (int c = 0; c < C1; c++) {
            float v = fmaf(a[c], la[c], lb[c]);
            a0 = fmaf(v, cv(w[(long)c * CO + j0]), a0);
            a1 = fmaf(v, cv(w[(long)c * CO + j0 + HALF]), a1);
        }
#pragma unroll 4
        for (int c = 0; c < C2; c++) {
            float v = fmaf(bb[c], la[C1 + c], lb[C1 + c]);
            a0 = fmaf(v, cv(w[(long)(C1 + c) * CO + j0]), a0);
            a1 = fmaf(v, cv(w[(long)(C1 + c) * CO + j0 + HALF]), a1);
        }
        if (ACT) { a0 = leaky(a0); a1 = leaky(a1); }
        Out[(long)n * CO + j0] = a0;
        Out[(long)n * CO + j0 + HALF] = a1;
    }
}

// ---------------- attention node (one wave = one node) ----------------
template <int CO>
__device__ __forceinline__ float attn_node(const float* th, const float* ou, const int* nbr, int n, int lane) {
    float r0 = th[(long)n * 128 + lane];
    float r1 = th[(long)n * 128 + 64 + lane];
    int mk[KNB]; float av[KNB];
#pragma unroll
    for (int k = 0; k < KNB; k++) {
        int m = nbr[n * KNB + k]; mk[k] = m;
        float v = fmaf(r0, th[(long)m * 128 + lane], r1 * th[(long)m * 128 + 64 + lane]);
#pragma unroll
        for (int off = 32; off > 0; off >>= 1) v += __shfl_xor(v, off, 64);
        av[k] = 1.f / (1.f + expf(-v));
    }
    float amax = av[0];
#pragma unroll
    for (int k = 1; k < KNB; k++) amax = fmaxf(amax, av[k]);
    float den = 0.f;
#pragma unroll
    for (int k = 0; k < KNB; k++) { av[k] = expf(av[k] - amax); den += av[k]; }
    float acc = 0.f;
    if (lane < CO) {
#pragma unroll
        for (int k = 0; k < KNB; k++) acc = fmaf(av[k], ou[(long)mk[k] * CO + lane], acc);
    }
    return leaky(acc / den);
}

__device__ void attn_e0(const float* TH_, const float* OU_, const int* nbr, float* E1, float* H2,
                        float* gsH2, float* gqH2, float* gsE, float* gqE, int gtid) {
    int lane = gtid & 63, wv = gtid >> 6;
    if (wv < N1 / 4) {
        float sE = 0.f, qE = 0.f, pooled = 0.f;
#pragma unroll
        for (int k = 0; k < 4; k++) {
            int n = (wv << 2) + k;
            float v = attn_node<64>(TH_, OU_, nbr, n, lane);
            E1[(long)n * 64 + lane] = v;
            sE += v; qE += v * v; pooled += v;
        }
        pooled *= 0.25f;
        H2[(long)wv * 64 + lane] = pooled;
        atomAdd(&gsE[lane], sE); atomAdd(&gqE[lane], qE);
        atomAdd(&gsH2[lane], pooled); atomAdd(&gqH2[lane], pooled * pooled);
    }
}

__device__ void attn_e1(const float* TH_, const float* OU_, const int* nbr, float* HD,
                        float* gs, float* gq, int gtid) {
    int lane = gtid & 63, wv = gtid >> 6;
    if (wv < N2) {
        float v = attn_node<32>(TH_, OU_, nbr, wv, lane);
        if (lane < 32) {
            HD[(long)wv * 32 + lane] = v;
            atomAdd(&gs[lane], v); atomAdd(&gq[lane], v * v);
        }
    }
}

__device__ void attn_d0(const float* TH_, const float* OU_, const int* nbr, float* HDE,
                        float* gs, float* gq, int gtid) {
    int lane = gtid & 63, wv = gtid >> 6;
    float s = 0.f, q = 0.f;
    for (int n = wv; n < N1; n += GSZ / 64) {
        float v = attn_node<64>(TH_, OU_, nbr, n, lane);
        HDE[(long)n * 64 + lane] = v;
        s += v; q += v * v;
    }
    atomAdd(&gs[lane], s); atomAdd(&gq[lane], q);
}

// ---------------- stage O': tail dw + classifier fused via LDS ----------------
template <typename T>
__device__ void dw_cls(const float* In, const T* dwp, const T* dbp, const T* wsw, const T* wb,
                       T* out, int b, int t, float* sm1) {
    const int o = t & 127;
    float wr[25];
#pragma unroll
    for (int i = 0; i < 25; i++) wr[i] = cv(dwp[o * 25 + i]);
    float bias = cv(dbp[o]);
    for (int it = 0; it < (N0 * 128) / GSZ; it++) {  // 16
        long ebase = (long)it * GSZ + (long)b * NTHR;
        int p = (int)((ebase + t) >> 7);
        int h = p >> 7, w = p & 127;
        float acc = bias;
#pragma unroll
        for (int dh = -2; dh <= 2; dh++) {
            int hh = h + dh;
            if ((unsigned)hh >= 128u) continue;
#pragma unroll
            for (int dv = -2; dv <= 2; dv++) {
                int ww = w + dv;
                if ((unsigned)ww >= 128u) continue;
                acc = fmaf(In[(long)(((hh << 7) + ww) << 7) + o], wr[(dh + 2) * 5 + (dv + 2)], acc);
            }
        }
        sm1[t] = leaky(acc);
        __syncthreads();
        if (t < (NTHR / 128) * 16) {   // 64 threads: 4 pixels x 16 classes
            int r = t >> 4, j = t & 15;
            const float* Fv = sm1 + r * 128;
            float lg = cv(wb[j]);
#pragma unroll 4
            for (int c = 0; c < 128; c++) lg = fmaf(Fv[c], cv(wsw[c * 16 + j]), lg);
            float m = lg;
#pragma unroll
            for (int s = 8; s > 0; s >>= 1) m = fmaxf(m, __shfl_xor(m, s, 16));
            float ex = expf(lg - m);
            float d = ex;
#pragma unroll
            for (int s = 8; s > 0; s >>= 1) d += __shfl_xor(d, s, 16);
            int p0 = (int)(ebase >> 7);
            stv(out, (long)(p0 + r) * 16 + j, ex / d);
        }
        __syncthreads();
    }
}

// ================= main cooperative kernel =================
__global__ __launch_bounds__(NTHR) void higcn3(Params p) {
    const int t = threadIdx.x, b = blockIdx.x;
    const int gtid = b * NTHR + t;
    __shared__ float sm1[NTHR], sm2[NTHR];

    float* W = p.W;
    int* ib = (int*)W;                            // barrier state: ints [0..2047]
    float* A0 = W + 2048; float* A1 = W + 2304;   // x sums (200)
    float* A2 = W + 2560; float* A3 = W + 2816;   // H1 sums (128)
    float* A4 = W + 3072; float* A5 = W + 3328;   // H2 sums (64)
    float* A6 = W + 3584; float* A7 = W + 3840;   // cat1 sums (96: 0..31 HD, 32..95 E1)
    float* A8 = W + 4096; float* A9 = W + 4352;   // cat2 sums (192: 0..63 HDE, 64..191 enc0)
    float* WtH = W + 8192;                        // 200x128 (ends 33792)
    float* WtT = W + 34816;                       // 192x128 (ends 59392)
    float* R0  = W + 65536;                       // 16384x128
    float* R1  = R0 + (long)N0 * 128;             // 16384x128 (enc0)
    float* H1  = R1 + (long)N0 * 128;             // 4096x128
    float* TH  = H1 + (long)N1 * 128;             // 4096x128
    float* OU  = TH + (long)N1 * 128;             // 4096x64
    float* E1  = OU + (long)N1 * 64;              // 4096x64
    float* H2  = E1 + (long)N1 * 64;              // 1024x64
    float* HD  = H2 + (long)N2 * 64;              // 1024x32
    float* HDE = HD + (long)N2 * 32;              // 4096x64

    // dtype detect (per-block, no global sync needed)
    {
        const unsigned short* u = (const unsigned short*)p.x;
        int cn = 0;
        for (int i = t; i < 4096; i += NTHR) cn += (((u[i] >> 7) & 0xFF) >= 0xC0);
        sm1[t] = (float)cn; __syncthreads();
        for (int k = NTHR / 2; k > 0; k >>= 1) { if (t < k) sm1[t] += sm1[t + k]; __syncthreads(); }
    }
    const bool F32 = sm1[0] > 32.f;
    __syncthreads();
    int gen = 0;

    // A: stats(x) + transposes
    if (F32) {
        statsX((const float*)p.x, A0, A1, b, t);
        transp((const float*)p.hpw, WtH, 200, gtid);
        transp((const float*)p.tpw, WtT, 192, gtid);
    } else {
        statsX((const bf16*)p.x, A0, A1, b, t);
        transp((const bf16*)p.hpw, WtH, 200, gtid);
        transp((const bf16*)p.tpw, WtT, 192, gtid);
    }
    gbar(ib, ++gen);

    // B: head GEMM
    if (F32) {
        derive_ab(A0, A1, (const float*)p.hg, (const float*)p.hb, 200, 1.f / N0, 1.f, sm1, sm2, t);
        head_gemm((const float*)p.x, WtH, (const float*)p.hpb, R0, sm1, sm2, gtid);
    } else {
        derive_ab(A0, A1, (const bf16*)p.hg, (const bf16*)p.hb, 200, 1.f / N0, 1.f, sm1, sm2, t);
        head_gemm((const bf16*)p.x, WtH, (const bf16*)p.hpb, R0, sm1, sm2, gtid);
    }
    gbar(ib, ++gen);

    // C: head dw + pool + stats(H1) + stats(enc0 -> cat2[64..191])
    if (F32) dw_head(R0, (const float*)p.hdw, (const float*)p.hdb, R1, H1, A2, A3, A8 + 64, A9 + 64, gtid, t, sm1, sm2);
    else     dw_head(R0, (const bf16*)p.hdw, (const bf16*)p.hdb, R1, H1, A2, A3, A8 + 64, A9 + 64, gtid, t, sm1, sm2);
    gbar(ib, ++gen);

    // E: e0 GEMMs
    if (F32) {
        derive_ab(A2, A3, (const float*)p.e0_g, (const float*)p.e0_b, 128, 1.f / N1, 1.f, sm1, sm2, t);
        std_gemm<float, 128, 128>(H1, (const float*)p.e0_wt, (const float*)p.e0_bt, TH, sm1, sm2, N1, gtid);
        std_gemm<float, 128, 64>(H1, (const float*)p.e0_wo, (const float*)p.e0_bo, OU, sm1, sm2, N1, gtid);
    } else {
        derive_ab(A2, A3, (const bf16*)p.e0_g, (const bf16*)p.e0_b, 128, 1.f / N1, 1.f, sm1, sm2, t);
        std_gemm<bf16, 128, 128>(H1, (const bf16*)p.e0_wt, (const bf16*)p.e0_bt, TH, sm1, sm2, N1, gtid);
        std_gemm<bf16, 128, 64>(H1, (const bf16*)p.e0_wo, (const bf16*)p.e0_bo, OU, sm1, sm2, N1, gtid);
    }
    gbar(ib, ++gen);

    // F: attn e0 + pool + stats(H2) + stats(E1 -> cat1[32..95])
    attn_e0(TH, OU, p.nbr_a, E1, H2, A4, A5, A6 + 32, A7 + 32, gtid);
    gbar(ib, ++gen);

    // H: e1 GEMMs
    if (F32) {
        derive_ab(A4, A5, (const float*)p.e1_g, (const float*)p.e1_b, 64, 1.f / N2, 1.f, sm1, sm2, t);
        std_gemm<float, 64, 128>(H2, (const float*)p.e1_wt, (const float*)p.e1_bt, TH, sm1, sm2, N2, gtid);
        std_gemm<float, 64, 32>(H2, (const float*)p.e1_wo, (const float*)p.e1_bo, OU, sm1, sm2, N2, gtid);
    } else {
        derive_ab(A4, A5, (const bf16*)p.e1_g, (const bf16*)p.e1_b, 64, 1.f / N2, 1.f, sm1, sm2, t);
        std_gemm<bf16, 64, 128>(H2, (const bf16*)p.e1_wt, (const bf16*)p.e1_bt, TH, sm1, sm2, N2, gtid);
        std_gemm<bf16, 64, 32>(H2, (const bf16*)p.e1_wo, (const bf16*)p.e1_bo, OU, sm1, sm2, N2, gtid);
    }
    gbar(ib, ++gen);

    // I: attn e1 + stats(HD -> cat1[0..31])
    attn_e1(TH, OU, p.nbr_b, HD, A6, A7, gtid);
    gbar(ib, ++gen);

    // K: d0 GEMMs (virtual concat)
    if (F32) {
        derive_ab(A6, A7, (const float*)p.d0_g, (const float*)p.d0_b, 32, 1.f / N1, 4.f, sm1, sm2, t);
        derive_ab(A6 + 32, A7 + 32, ((const float*)p.d0_g) + 32, ((const float*)p.d0_b) + 32, 64, 1.f / N1, 1.f, sm1 + 32, sm2 + 32, t);
        cat_gemm<float, float, 32, 64, 128, false>(HD, E1, (const float*)p.d0_wt, (const float*)p.d0_bt, TH, sm1, sm2, N1, gtid);
        cat_gemm<float, float, 32, 64, 64, false>(HD, E1, (const float*)p.d0_wo, (const float*)p.d0_bo, OU, sm1, sm2, N1, gtid);
    } else {
        derive_ab(A6, A7, (const bf16*)p.d0_g, (const bf16*)p.d0_b, 32, 1.f / N1, 4.f, sm1, sm2, t);
        derive_ab(A6 + 32, A7 + 32, ((const bf16*)p.d0_g) + 32, ((const bf16*)p.d0_b) + 32, 64, 1.f / N1, 1.f, sm1 + 32, sm2 + 32, t);
        cat_gemm<bf16, bf16, 32, 64, 128, false>(HD, E1, (const bf16*)p.d0_wt, (const bf16*)p.d0_bt, TH, sm1, sm2, N1, gtid);
        cat_gemm<bf16, bf16, 32, 64, 64, false>(HD, E1, (const bf16*)p.d0_wo, (const bf16*)p.d0_bo, OU, sm1, sm2, N1, gtid);
    }
    gbar(ib, ++gen);

    // L: attn d0 + stats(HDE -> cat2[0..63])
    attn_d0(TH, OU, p.nbr_a, HDE, A8, A9, gtid);
    gbar(ib, ++gen);

    // N: tail GEMM (virtual concat, transposed weights)
    if (F32) {
        derive_ab(A8, A9, (const float*)p.tg, (const float*)p.tb, 64, 1.f / N0, 4.f, sm1, sm2, t);
        derive_ab(A8 + 64, A9 + 64, ((const float*)p.tg) + 64, ((const float*)p.tb) + 64, 128, 1.f / N0, 1.f, sm1 + 64, sm2 + 64, t);
        cat_gemm<float, float, 64, 128, 128, true>(HDE, R1, WtT, (const float*)p.tpb, R0, sm1, sm2, N0, gtid);
    } else {
        derive_ab(A8, A9, (const bf16*)p.tg, (const bf16*)p.tb, 64, 1.f / N0, 4.f, sm1, sm2, t);
        derive_ab(A8 + 64, A9 + 64, ((const bf16*)p.tg) + 64, ((const bf16*)p.tb) + 64, 128, 1.f / N0, 1.f, sm1 + 64, sm2 + 64, t);
        cat_gemm<float, bf16, 64, 128, 128, true>(HDE, R1, WtT, (const bf16*)p.tpb, R0, sm1, sm2, N0, gtid);
    }
    gbar(ib, ++gen);

    // O': tail dw + classifier
    if (F32) dw_cls(R0, (const float*)p.tdw, (const float*)p.tdb, (const float*)p.wsw, (const float*)p.wb, (float*)p.out, b, t, sm1);
    else     dw_cls(R0, (const bf16*)p.tdw, (const bf16*)p.tdb, (const bf16*)p.wsw, (const bf16*)p.wb, (bf16*)p.out, b, t, sm1);
}

// ---------------- init: zero barrier + accumulators ----------------
__global__ void init_ws(float* W) {
    int i = blockIdx.x * 256 + threadIdx.x;
    if (i < 8192) W[i] = 0.f;
}

// ================= host side =================
extern "C" void kernel_launch(void* const* d_in, const int* in_sizes, int n_in,
                              void* d_out, int out_size, void* d_ws, size_t ws_size,
                              hipStream_t stream) {
    bool dict = (in_sizes[1] > 1000000);
    int I_x, I_nbr_a, I_nbr_b, I_hg, I_ws, I_e0, I_e1, I_d0, I_tg;
    if (dict) {
        I_x = 0; I_nbr_a = 5; I_nbr_b = 6; I_hg = 7; I_e0 = 13; I_e1 = 19; I_d0 = 25; I_tg = 31; I_ws = 37;
    } else {
        I_x = 0; I_hg = 1; I_e0 = 7; I_e1 = 13; I_d0 = 19; I_tg = 25; I_ws = 31; I_nbr_a = 37; I_nbr_b = 38;
    }
    Params prm;
    prm.x = d_in[I_x];
    prm.nbr_a = (const int*)d_in[I_nbr_a];
    prm.nbr_b = (const int*)d_in[I_nbr_b];
    prm.hg = d_in[I_hg + 0]; prm.hb = d_in[I_hg + 1]; prm.hpw = d_in[I_hg + 2];
    prm.hpb = d_in[I_hg + 3]; prm.hdw = d_in[I_hg + 4]; prm.hdb = d_in[I_hg + 5];
    prm.e0_g = d_in[I_e0 + 0]; prm.e0_b = d_in[I_e0 + 1]; prm.e0_wt = d_in[I_e0 + 2];
    prm.e0_bt = d_in[I_e0 + 3]; prm.e0_wo = d_in[I_e0 + 4]; prm.e0_bo = d_in[I_e0 + 5];
    prm.e1_g = d_in[I_e1 + 0]; prm.e1_b = d_in[I_e1 + 1]; prm.e1_wt = d_in[I_e1 + 2];
    prm.e1_bt = d_in[I_e1 + 3]; prm.e1_wo = d_in[I_e1 + 4]; prm.e1_bo = d_in[I_e1 + 5];
    prm.d0_g = d_in[I_d0 + 0]; prm.d0_b = d_in[I_d0 + 1]; prm.d0_wt = d_in[I_d0 + 2];
    prm.d0_bt = d_in[I_d0 + 3]; prm.d0_wo = d_in[I_d0 + 4]; prm.d0_bo = d_in[I_d0 + 5];
    prm.tg = d_in[I_tg + 0]; prm.tb = d_in[I_tg + 1]; prm.tpw = d_in[I_tg + 2];
    prm.tpb = d_in[I_tg + 3]; prm.tdw = d_in[I_tg + 4]; prm.tdb = d_in[I_tg + 5];
    prm.wsw = d_in[I_ws + 0]; prm.wb = d_in[I_ws + 1];
    prm.out = d_out;
    prm.W = (float*)d_ws;

    init_ws<<<32, 256, 0, stream>>>((float*)d_ws);
    void* args[] = { (void*)&prm };
    hipLaunchCooperativeKernel((const void*)higcn3, dim3(NBLK), dim3(NTHR), args, 0, stream);
}

// Round 6
// 1147.822 us; speedup vs baseline: 2.0991x; 1.0350x over previous
//
#include <hip/hip_runtime.h>
#include <hip/hip_bf16.h>
#include <math.h>

using bf16 = __hip_bfloat16;

#define H_IMG 128
#define W_IMG 128
#define C_IN  200
#define NCLS  16
#define N0    16384
#define N1    4096
#define N2    1024
#define KNB   16
#define EPS   1e-5f
#define SLOPE 0.01f

#define NBLK  256
#define NTHR  512
#define GSZ   (NBLK * NTHR)   // 131072 threads, 2048 waves

// barrier int slots (128B apart where contended)
#define ROOT0 0
#define REL0  32
#define GRP0  64          // 32 groups: 64 + g*32, ends 1056
#define ROOT1 1088
#define REL1  1120
#define XARR  1152        // 8 XCDs: 1152 + x*32, ends 1376
#define BCNT  1408        // 8 XCDs: 1408 + x*32, ends 1632
#define NXCD  1664

__device__ __forceinline__ float leaky(float v) { return v >= 0.f ? v : SLOPE * v; }
__device__ __forceinline__ float cv(float v) { return v; }
__device__ __forceinline__ float cv(bf16 v) { return __bfloat162float(v); }
__device__ __forceinline__ void stv(float* p, long i, float v) { p[i] = v; }
__device__ __forceinline__ void stv(bf16* p, long i, float v) { p[i] = __float2bfloat16(v); }
__device__ __forceinline__ void atomAdd(float* p, float v) { unsafeAtomicAdd(p, v); }

__device__ __forceinline__ unsigned get_xcd() {
    unsigned x;
    asm volatile("s_getreg_b32 %0, hwreg(HW_REG_XCC_ID)" : "=s"(x));
    return x & 7u;
}
__device__ __forceinline__ int aadd(int* p) {
    return __hip_atomic_fetch_add(p, 1, __ATOMIC_RELAXED, __HIP_MEMORY_SCOPE_AGENT);
}
__device__ __forceinline__ int ald(const int* p) {
    return __hip_atomic_load(p, __ATOMIC_RELAXED, __HIP_MEMORY_SCOPE_AGENT);
}

struct Params {
    const void *x; const int *nbr_a, *nbr_b;
    const void *hg,*hb,*hpw,*hpb,*hdw,*hdb;
    const void *e0_g,*e0_b,*e0_wt,*e0_bt,*e0_wo,*e0_bo;
    const void *e1_g,*e1_b,*e1_wt,*e1_bt,*e1_wo,*e1_bo;
    const void *d0_g,*d0_b,*d0_wt,*d0_bt,*d0_wo,*d0_bo;
    const void *tg,*tb,*tpw,*tpb,*tdw,*tdb,*wsw,*wb;
    void* out; float* W;
};

// plain count barrier (no cache maintenance) — used once to seal XCD registration
__device__ __forceinline__ void gbar_plain(int* ib) {
    __syncthreads();
    if (threadIdx.x == 0) {
        int g = blockIdx.x >> 3;
        int prev = aadd(&ib[GRP0 + g * 32]);
        if (prev == 7) {
            int r = aadd(&ib[ROOT0]);
            if (r == 31) __hip_atomic_store(&ib[REL0], 1, __ATOMIC_RELAXED, __HIP_MEMORY_SCOPE_AGENT);
        }
        while (ald(&ib[REL0]) < 1) __builtin_amdgcn_s_sleep(4);
    }
    __syncthreads();
}

// flush barrier: exactly ONE buffer_wbl2 per XCD (the expensive part), acquire-inv per block
__device__ __forceinline__ void gbar_flush(int* ib, int gen, unsigned xcd, int bc, int nx) {
    __syncthreads();
    if (threadIdx.x == 0) {
        int prev = aadd(&ib[XARR + xcd * 32]);
        if (prev == gen * bc - 1) {                              // last block of this XCD this generation
            __builtin_amdgcn_fence(__ATOMIC_RELEASE, "agent");   // wbl2: flush this XCD's whole L2 to LLC
            int r = aadd(&ib[ROOT1]);
            if (r == gen * nx - 1)
                __hip_atomic_store(&ib[REL1], gen, __ATOMIC_RELAXED, __HIP_MEMORY_SCOPE_AGENT);
        }
        while (ald(&ib[REL1]) < gen) __builtin_amdgcn_s_sleep(4);
        __builtin_amdgcn_fence(__ATOMIC_ACQUIRE, "agent");       // inv L1/L2 (flash, writes nothing back)
    }
    __syncthreads();
}

// ---------------- derive alpha/beta from sums into LDS ----------------
template <typename T>
__device__ __forceinline__ void derive_ab(const float* gs, const float* gq, const T* g, const T* bb,
                                          int C, float invP, float rep, float* la, float* lb, int t) {
    if (t < C) {
        float mu = gs[t] * rep * invP;
        float var = gq[t] * rep * invP - mu * mu;
        float a = rsqrtf(var + EPS) * cv(g[t]);
        la[t] = a; lb[t] = cv(bb[t]) - mu * a;
    }
    __syncthreads();
}

// ---------------- stage A: stats over x + weight transposes ----------------
template <typename T>
__device__ void statsX(const T* x, float* gs, float* gq, int b, int t) {
    if (t < C_IN) {
        float s = 0.f, q = 0.f;
        int r0 = b * (N0 / NBLK);
        for (int r = 0; r < N0 / NBLK; r++) {
            float v = cv(x[(long)(r0 + r) * C_IN + t]);
            s += v; q += v * v;
        }
        atomAdd(&gs[t], s); atomAdd(&gq[t], q);
    }
}

template <typename T>
__device__ void transp(const T* src, float* dst, int CI, int gtid) { // src [128][CI] -> dst [CI][128]
    for (int i = gtid; i < CI * 128; i += GSZ) {
        int j = i & 127, c = i >> 7;
        dst[i] = cv(src[j * CI + c]);
    }
}

// ---------------- stage B: head GEMM (BN inline), 2-col tile ----------------
template <typename T>
__device__ void head_gemm(const T* x, const float* Wt, const T* bias, float* Out,
                          const float* la, const float* lb, int gtid) {
    for (long i = gtid; i < (long)N0 * 64; i += GSZ) {
        int n = (int)(i >> 6), j0 = (int)(i & 63);
        const T* in = x + (long)n * C_IN;
        float a0 = cv(bias[j0]), a1 = cv(bias[j0 + 64]);
#pragma unroll 4
        for (int c = 0; c < C_IN; c++) {
            float v = fmaf(cv(in[c]), la[c], lb[c]);
            a0 = fmaf(v, Wt[c * 128 + j0], a0);
            a1 = fmaf(v, Wt[c * 128 + j0 + 64], a1);
        }
        Out[(long)n * 128 + j0] = leaky(a0);
        Out[(long)n * 128 + j0 + 64] = leaky(a1);
    }
}

// ---------------- stage C: head dw 5x5 + pool4 + fused stats (H1, enc0) ----------------
template <typename T>
__device__ void dw_head(const float* In, const T* dwp, const T* dbp, float* R1, float* H1,
                        float* gsH, float* gqH, float* gsR, float* gqR,
                        int gtid, int t, float* sm1, float* sm2) {
    const int o = gtid & 127;
    float wr[25];
#pragma unroll
    for (int i = 0; i < 25; i++) wr[i] = cv(dwp[o * 25 + i]);
    float bias = cv(dbp[o]);
    float sH = 0.f, qH = 0.f, sR = 0.f, qR = 0.f;
    for (long e = gtid; e < (long)(N0 / 4) * 128; e += GSZ) {
        int n = (int)(e >> 7);
        int pp0 = n << 2;
        int h = pp0 >> 7, w0 = pp0 & 127;
        float pooled = 0.f;
#pragma unroll
        for (int k = 0; k < 4; k++) {
            int w = w0 + k;
            float acc = bias;
#pragma unroll
            for (int dh = -2; dh <= 2; dh++) {
                int hh = h + dh;
                if ((unsigned)hh >= 128u) continue;
#pragma unroll
                for (int dv = -2; dv <= 2; dv++) {
                    int ww = w + dv;
                    if ((unsigned)ww >= 128u) continue;
                    acc = fmaf(In[(long)(((hh << 7) + ww) << 7) + o], wr[(dh + 2) * 5 + (dv + 2)], acc);
                }
            }
            float lk = leaky(acc);
            R1[(long)(pp0 + k) * 128 + o] = lk;
            sR += lk; qR += lk * lk; pooled += lk;
        }
        pooled *= 0.25f;
        H1[(long)n * 128 + o] = pooled;
        sH += pooled; qH += pooled * pooled;
    }
    sm1[t] = sH; sm2[t] = qH; __syncthreads();
    if (t < 256) { sm1[t] += sm1[t + 256]; sm2[t] += sm2[t + 256]; } __syncthreads();
    if (t < 128) { atomAdd(&gsH[t], sm1[t] + sm1[t + 128]); atomAdd(&gqH[t], sm2[t] + sm2[t + 128]); }
    __syncthreads();
    sm1[t] = sR; sm2[t] = qR; __syncthreads();
    if (t < 256) { sm1[t] += sm1[t + 256]; sm2[t] += sm2[t + 256]; } __syncthreads();
    if (t < 128) { atomAdd(&gsR[t], sm1[t] + sm1[t + 128]); atomAdd(&gqR[t], sm2[t] + sm2[t + 128]); }
    __syncthreads();
}

// ---------------- generic 2-col GEMM with inline BN ----------------
template <typename TW, int CI, int CO>
__device__ void std_gemm(const float* In, const TW* w, const TW* bias, float* Out,
                         const float* la, const float* lb, int N, int gtid) {
    const int HALF = CO / 2;
    for (long i = gtid; i < (long)N * HALF; i += GSZ) {
        int n = (int)(i / HALF);
        int j0 = (int)(i - (long)n * HALF);
        const float* in = In + (long)n * CI;
        float a0 = cv(bias[j0]), a1 = cv(bias[j0 + HALF]);
#pragma unroll 4
        for (int c = 0; c < CI; c++) {
            float v = fmaf(in[c], la[c], lb[c]);
            a0 = fmaf(v, cv(w[(long)c * CO + j0]), a0);
            a1 = fmaf(v, cv(w[(long)c * CO + j0 + HALF]), a1);
        }
        Out[(long)n * CO + j0] = a0;
        Out[(long)n * CO + j0 + HALF] = a1;
    }
}

// ---------------- concat-input 2-col GEMM ----------------
template <typename TW, typename TB, int C1, int C2, int CO, bool ACT>
__device__ void cat_gemm(const float* A, const float* B, const TW* w, const TB* bias, float* Out,
                         const float* la, const float* lb, int N, int gtid) {
    const int HALF = CO / 2;
    for (long i = gtid; i < (long)N * HALF; i += GSZ) {
        int n = (int)(i / HALF);
        int j0 = (int)(i - (long)n * HALF);
        const float* a = A + (long)(n >> 2) * C1;
        const float* bb = B + (long)n * C2;
        float a0 = cv(bias[j0]), a1 = cv(bias[j0 + HALF]);
#pragma unroll 4
        for (int c = 0; c < C1; c++) {
            float v = fmaf(a[c], la[c], lb[c]);
            a0 = fmaf(v, cv(w[(long)c * CO + j0]), a0);
            a1 = fmaf(v, cv(w[(long)c * CO + j0 + HALF]), a1);
        }
#pragma unroll 4
        for (int c = 0; c < C2; c++) {
            float v = fmaf(bb[c], la[C1 + c], lb[C1 + c]);
            a0 = fmaf(v, cv(w[(long)(C1 + c) * CO + j0]), a0);
            a1 = fmaf(v, cv(w[(long)(C1 + c) * CO + j0 + HALF]), a1);
        }
        if (ACT) { a0 = leaky(a0); a1 = leaky(a1); }
        Out[(long)n * CO + j0] = a0;
        Out[(long)n * CO + j0 + HALF] = a1;
    }
}

// ---------------- attention node (one wave = one node) ----------------
template <int CO>
__device__ __forceinline__ float attn_node(const float* th, const float* ou, const int* nbr, int n, int lane) {
    float r0 = th[(long)n * 128 + lane];
    float r1 = th[(long)n * 128 + 64 + lane];
    int mk[KNB]; float av[KNB];
#pragma unroll
    for (int k = 0; k < KNB; k++) {
        int m = nbr[n * KNB + k]; mk[k] = m;
        float v = fmaf(r0, th[(long)m * 128 + lane], r1 * th[(long)m * 128 + 64 + lane]);
#pragma unroll
        for (int off = 32; off > 0; off >>= 1) v += __shfl_xor(v, off, 64);
        av[k] = 1.f / (1.f + expf(-v));
    }
    float amax = av[0];
#pragma unroll
    for (int k = 1; k < KNB; k++) amax = fmaxf(amax, av[k]);
    float den = 0.f;
#pragma unroll
    for (int k = 0; k < KNB; k++) { av[k] = expf(av[k] - amax); den += av[k]; }
    float acc = 0.f;
    if (lane < CO) {
#pragma unroll
        for (int k = 0; k < KNB; k++) acc = fmaf(av[k], ou[(long)mk[k] * CO + lane], acc);
    }
    return leaky(acc / den);
}

__device__ void attn_e0(const float* TH_, const float* OU_, const int* nbr, float* E1, float* H2,
                        float* gsH2, float* gqH2, float* gsE, float* gqE, int gtid) {
    int lane = gtid & 63, wv = gtid >> 6;
    if (wv < N1 / 4) {
        float sE = 0.f, qE = 0.f, pooled = 0.f;
#pragma unroll
        for (int k = 0; k < 4; k++) {
            int n = (wv << 2) + k;
            float v = attn_node<64>(TH_, OU_, nbr, n, lane);
            E1[(long)n * 64 + lane] = v;
            sE += v; qE += v * v; pooled += v;
        }
        pooled *= 0.25f;
        H2[(long)wv * 64 + lane] = pooled;
        atomAdd(&gsE[lane], sE); atomAdd(&gqE[lane], qE);
        atomAdd(&gsH2[lane], pooled); atomAdd(&gqH2[lane], pooled * pooled);
    }
}

__device__ void attn_e1(const float* TH_, const float* OU_, const int* nbr, float* HD,
                        float* gs, float* gq, int gtid) {
    int lane = gtid & 63, wv = gtid >> 6;
    if (wv < N2) {
        float v = attn_node<32>(TH_, OU_, nbr, wv, lane);
        if (lane < 32) {
            HD[(long)wv * 32 + lane] = v;
            atomAdd(&gs[lane], v); atomAdd(&gq[lane], v * v);
        }
    }
}

__device__ void attn_d0(const float* TH_, const float* OU_, const int* nbr, float* HDE,
                        float* gs, float* gq, int gtid) {
    int lane = gtid & 63, wv = gtid >> 6;
    float s = 0.f, q = 0.f;
    for (int n = wv; n < N1; n += GSZ / 64) {
        float v = attn_node<64>(TH_, OU_, nbr, n, lane);
        HDE[(long)n * 64 + lane] = v;
        s += v; q += v * v;
    }
    atomAdd(&gs[lane], s); atomAdd(&gq[lane], q);
}

// ---------------- stage O': tail dw + classifier fused via LDS ----------------
template <typename T>
__device__ void dw_cls(const float* In, const T* dwp, const T* dbp, const T* wsw, const T* wb,
                       T* out, int b, int t, float* sm1) {
    const int o = t & 127;
    float wr[25];
#pragma unroll
    for (int i = 0; i < 25; i++) wr[i] = cv(dwp[o * 25 + i]);
    float bias = cv(dbp[o]);
    for (int it = 0; it < (N0 * 128) / GSZ; it++) {  // 16
        long ebase = (long)it * GSZ + (long)b * NTHR;
        int p = (int)((ebase + t) >> 7);
        int h = p >> 7, w = p & 127;
        float acc = bias;
#pragma unroll
        for (int dh = -2; dh <= 2; dh++) {
            int hh = h + dh;
            if ((unsigned)hh >= 128u) continue;
#pragma unroll
            for (int dv = -2; dv <= 2; dv++) {
                int ww = w + dv;
                if ((unsigned)ww >= 128u) continue;
                acc = fmaf(In[(long)(((hh << 7) + ww) << 7) + o], wr[(dh + 2) * 5 + (dv + 2)], acc);
            }
        }
        sm1[t] = leaky(acc);
        __syncthreads();
        if (t < (NTHR / 128) * 16) {   // 64 threads: 4 pixels x 16 classes
            int r = t >> 4, j = t & 15;
            const float* Fv = sm1 + r * 128;
            float lg = cv(wb[j]);
#pragma unroll 4
            for (int c = 0; c < 128; c++) lg = fmaf(Fv[c], cv(wsw[c * 16 + j]), lg);
            float m = lg;
#pragma unroll
            for (int s = 8; s > 0; s >>= 1) m = fmaxf(m, __shfl_xor(m, s, 16));
            float ex = expf(lg - m);
            float d = ex;
#pragma unroll
            for (int s = 8; s > 0; s >>= 1) d += __shfl_xor(d, s, 16);
            int p0 = (int)(ebase >> 7);
            stv(out, (long)(p0 + r) * 16 + j, ex / d);
        }
        __syncthreads();
    }
}

// ================= main cooperative kernel =================
__global__ __launch_bounds__(NTHR) void higcn4(Params p) {
    const int t = threadIdx.x, b = blockIdx.x;
    const int gtid = b * NTHR + t;
    __shared__ float sm1[NTHR], sm2[NTHR];

    float* W = p.W;
    int* ib = (int*)W;                            // barrier state: ints [0..2047]
    float* A0 = W + 2048; float* A1 = W + 2304;   // x sums (200)
    float* A2 = W + 2560; float* A3 = W + 2816;   // H1 sums (128)
    float* A4 = W + 3072; float* A5 = W + 3328;   // H2 sums (64)
    float* A6 = W + 3584; float* A7 = W + 3840;   // cat1 sums (96: 0..31 HD, 32..95 E1)
    float* A8 = W + 4096; float* A9 = W + 4352;   // cat2 sums (192: 0..63 HDE, 64..191 enc0)
    float* WtH = W + 8192;                        // 200x128
    float* WtT = W + 34816;                       // 192x128
    float* R0  = W + 65536;                       // 16384x128
    float* R1  = R0 + (long)N0 * 128;             // 16384x128 (enc0)
    float* H1  = R1 + (long)N0 * 128;             // 4096x128
    float* TH  = H1 + (long)N1 * 128;             // 4096x128
    float* OU  = TH + (long)N1 * 128;             // 4096x64
    float* E1  = OU + (long)N1 * 64;              // 4096x64
    float* H2  = E1 + (long)N1 * 64;              // 1024x64
    float* HD  = H2 + (long)N2 * 64;              // 1024x32
    float* HDE = HD + (long)N2 * 32;              // 4096x64

    // XCD registration (dynamic block->XCD census; no mapping assumptions)
    const unsigned xcd = get_xcd();
    if (t == 0) {
        int prev = aadd(&ib[BCNT + xcd * 32]);
        if (prev == 0) aadd(&ib[NXCD]);
    }

    // dtype detect (per-block, no global sync needed)
    {
        const unsigned short* u = (const unsigned short*)p.x;
        int cn = 0;
        for (int i = t; i < 4096; i += NTHR) cn += (((u[i] >> 7) & 0xFF) >= 0xC0);
        sm1[t] = (float)cn; __syncthreads();
        for (int k = NTHR / 2; k > 0; k >>= 1) { if (t < k) sm1[t] += sm1[t + k]; __syncthreads(); }
    }
    const bool F32 = sm1[0] > 32.f;
    __syncthreads();

    gbar_plain(ib);   // seal registration
    int bc = 0, nx = 0;
    if (t == 0) { bc = ald(&ib[BCNT + xcd * 32]); nx = ald(&ib[NXCD]); }
    int gen = 0;

    // A: stats(x) + transposes
    if (F32) {
        statsX((const float*)p.x, A0, A1, b, t);
        transp((const float*)p.hpw, WtH, 200, gtid);
        transp((const float*)p.tpw, WtT, 192, gtid);
    } else {
        statsX((const bf16*)p.x, A0, A1, b, t);
        transp((const bf16*)p.hpw, WtH, 200, gtid);
        transp((const bf16*)p.tpw, WtT, 192, gtid);
    }
    gbar_flush(ib, ++gen, xcd, bc, nx);

    // B: head GEMM
    if (F32) {
        derive_ab(A0, A1, (const float*)p.hg, (const float*)p.hb, 200, 1.f / N0, 1.f, sm1, sm2, t);
        head_gemm((const float*)p.x, WtH, (const float*)p.hpb, R0, sm1, sm2, gtid);
    } else {
        derive_ab(A0, A1, (const bf16*)p.hg, (const bf16*)p.hb, 200, 1.f / N0, 1.f, sm1, sm2, t);
        head_gemm((const bf16*)p.x, WtH, (const bf16*)p.hpb, R0, sm1, sm2, gtid);
    }
    gbar_flush(ib, ++gen, xcd, bc, nx);

    // C: head dw + pool + stats(H1) + stats(enc0 -> cat2[64..191])
    if (F32) dw_head(R0, (const float*)p.hdw, (const float*)p.hdb, R1, H1, A2, A3, A8 + 64, A9 + 64, gtid, t, sm1, sm2);
    else     dw_head(R0, (const bf16*)p.hdw, (const bf16*)p.hdb, R1, H1, A2, A3, A8 + 64, A9 + 64, gtid, t, sm1, sm2);
    gbar_flush(ib, ++gen, xcd, bc, nx);

    // E: e0 GEMMs
    if (F32) {
        derive_ab(A2, A3, (const float*)p.e0_g, (const float*)p.e0_b, 128, 1.f / N1, 1.f, sm1, sm2, t);
        std_gemm<float, 128, 128>(H1, (const float*)p.e0_wt, (const float*)p.e0_bt, TH, sm1, sm2, N1, gtid);
        std_gemm<float, 128, 64>(H1, (const float*)p.e0_wo, (const float*)p.e0_bo, OU, sm1, sm2, N1, gtid);
    } else {
        derive_ab(A2, A3, (const bf16*)p.e0_g, (const bf16*)p.e0_b, 128, 1.f / N1, 1.f, sm1, sm2, t);
        std_gemm<bf16, 128, 128>(H1, (const bf16*)p.e0_wt, (const bf16*)p.e0_bt, TH, sm1, sm2, N1, gtid);
        std_gemm<bf16, 128, 64>(H1, (const bf16*)p.e0_wo, (const bf16*)p.e0_bo, OU, sm1, sm2, N1, gtid);
    }
    gbar_flush(ib, ++gen, xcd, bc, nx);

    // F: attn e0 + pool + stats(H2) + stats(E1 -> cat1[32..95])
    attn_e0(TH, OU, p.nbr_a, E1, H2, A4, A5, A6 + 32, A7 + 32, gtid);
    gbar_flush(ib, ++gen, xcd, bc, nx);

    // H: e1 GEMMs
    if (F32) {
        derive_ab(A4, A5, (const float*)p.e1_g, (const float*)p.e1_b, 64, 1.f / N2, 1.f, sm1, sm2, t);
        std_gemm<float, 64, 128>(H2, (const float*)p.e1_wt, (const float*)p.e1_bt, TH, sm1, sm2, N2, gtid);
        std_gemm<float, 64, 32>(H2, (const float*)p.e1_wo, (const float*)p.e1_bo, OU, sm1, sm2, N2, gtid);
    } else {
        derive_ab(A4, A5, (const bf16*)p.e1_g, (const bf16*)p.e1_b, 64, 1.f / N2, 1.f, sm1, sm2, t);
        std_gemm<bf16, 64, 128>(H2, (const bf16*)p.e1_wt, (const bf16*)p.e1_bt, TH, sm1, sm2, N2, gtid);
        std_gemm<bf16, 64, 32>(H2, (const bf16*)p.e1_wo, (const bf16*)p.e1_bo, OU, sm1, sm2, N2, gtid);
    }
    gbar_flush(ib, ++gen, xcd, bc, nx);

    // I: attn e1 + stats(HD -> cat1[0..31])
    attn_e1(TH, OU, p.nbr_b, HD, A6, A7, gtid);
    gbar_flush(ib, ++gen, xcd, bc, nx);

    // K: d0 GEMMs (virtual concat)
    if (F32) {
        derive_ab(A6, A7, (const float*)p.d0_g, (const float*)p.d0_b, 32, 1.f / N1, 4.f, sm1, sm2, t);
        derive_ab(A6 + 32, A7 + 32, ((const float*)p.d0_g) + 32, ((const float*)p.d0_b) + 32, 64, 1.f / N1, 1.f, sm1 + 32, sm2 + 32, t);
        cat_gemm<float, float, 32, 64, 128, false>(HD, E1, (const float*)p.d0_wt, (const float*)p.d0_bt, TH, sm1, sm2, N1, gtid);
        cat_gemm<float, float, 32, 64, 64, false>(HD, E1, (const float*)p.d0_wo, (const float*)p.d0_bo, OU, sm1, sm2, N1, gtid);
    } else {
        derive_ab(A6, A7, (const bf16*)p.d0_g, (const bf16*)p.d0_b, 32, 1.f / N1, 4.f, sm1, sm2, t);
        derive_ab(A6 + 32, A7 + 32, ((const bf16*)p.d0_g) + 32, ((const bf16*)p.d0_b) + 32, 64, 1.f / N1, 1.f, sm1 + 32, sm2 + 32, t);
        cat_gemm<bf16, bf16, 32, 64, 128, false>(HD, E1, (const bf16*)p.d0_wt, (const bf16*)p.d0_bt, TH, sm1, sm2, N1, gtid);
        cat_gemm<bf16, bf16, 32, 64, 64, false>(HD, E1, (const bf16*)p.d0_wo, (const bf16*)p.d0_bo, OU, sm1, sm2, N1, gtid);
    }
    gbar_flush(ib, ++gen, xcd, bc, nx);

    // L: attn d0 + stats(HDE -> cat2[0..63])
    attn_d0(TH, OU, p.nbr_a, HDE, A8, A9, gtid);
    gbar_flush(ib, ++gen, xcd, bc, nx);

    // N: tail GEMM (virtual concat, transposed weights)
    if (F32) {
        derive_ab(A8, A9, (const float*)p.tg, (const float*)p.tb, 64, 1.f / N0, 4.f, sm1, sm2, t);
        derive_ab(A8 + 64, A9 + 64, ((const float*)p.tg) + 64, ((const float*)p.tb) + 64, 128, 1.f / N0, 1.f, sm1 + 64, sm2 + 64, t);
        cat_gemm<float, float, 64, 128, 128, true>(HDE, R1, WtT, (const float*)p.tpb, R0, sm1, sm2, N0, gtid);
    } else {
        derive_ab(A8, A9, (const bf16*)p.tg, (const bf16*)p.tb, 64, 1.f / N0, 4.f, sm1, sm2, t);
        derive_ab(A8 + 64, A9 + 64, ((const bf16*)p.tg) + 64, ((const bf16*)p.tb) + 64, 128, 1.f / N0, 1.f, sm1 + 64, sm2 + 64, t);
        cat_gemm<float, bf16, 64, 128, 128, true>(HDE, R1, WtT, (const bf16*)p.tpb, R0, sm1, sm2, N0, gtid);
    }
    gbar_flush(ib, ++gen, xcd, bc, nx);

    // O': tail dw + classifier
    if (F32) dw_cls(R0, (const float*)p.tdw, (const float*)p.tdb, (const float*)p.wsw, (const float*)p.wb, (float*)p.out, b, t, sm1);
    else     dw_cls(R0, (const bf16*)p.tdw, (const bf16*)p.tdb, (const bf16*)p.wsw, (const bf16*)p.wb, (bf16*)p.out, b, t, sm1);
}

// ---------------- init: zero barrier + accumulators ----------------
__global__ void init_ws(float* W) {
    int i = blockIdx.x * 256 + threadIdx.x;
    if (i < 8192) W[i] = 0.f;
}

// ================= host side =================
extern "C" void kernel_launch(void* const* d_in, const int* in_sizes, int n_in,
                              void* d_out, int out_size, void* d_ws, size_t ws_size,
                              hipStream_t stream) {
    bool dict = (in_sizes[1] > 1000000);
    int I_x, I_nbr_a, I_nbr_b, I_hg, I_ws, I_e0, I_e1, I_d0, I_tg;
    if (dict) {
        I_x = 0; I_nbr_a = 5; I_nbr_b = 6; I_hg = 7; I_e0 = 13; I_e1 = 19; I_d0 = 25; I_tg = 31; I_ws = 37;
    } else {
        I_x = 0; I_hg = 1; I_e0 = 7; I_e1 = 13; I_d0 = 19; I_tg = 25; I_ws = 31; I_nbr_a = 37; I_nbr_b = 38;
    }
    Params prm;
    prm.x = d_in[I_x];
    prm.nbr_a = (const int*)d_in[I_nbr_a];
    prm.nbr_b = (const int*)d_in[I_nbr_b];
    prm.hg = d_in[I_hg + 0]; prm.hb = d_in[I_hg + 1]; prm.hpw = d_in[I_hg + 2];
    prm.hpb = d_in[I_hg + 3]; prm.hdw = d_in[I_hg + 4]; prm.hdb = d_in[I_hg + 5];
    prm.e0_g = d_in[I_e0 + 0]; prm.e0_b = d_in[I_e0 + 1]; prm.e0_wt = d_in[I_e0 + 2];
    prm.e0_bt = d_in[I_e0 + 3]; prm.e0_wo = d_in[I_e0 + 4]; prm.e0_bo = d_in[I_e0 + 5];
    prm.e1_g = d_in[I_e1 + 0]; prm.e1_b = d_in[I_e1 + 1]; prm.e1_wt = d_in[I_e1 + 2];
    prm.e1_bt = d_in[I_e1 + 3]; prm.e1_wo = d_in[I_e1 + 4]; prm.e1_bo = d_in[I_e1 + 5];
    prm.d0_g = d_in[I_d0 + 0]; prm.d0_b = d_in[I_d0 + 1]; prm.d0_wt = d_in[I_d0 + 2];
    prm.d0_bt = d_in[I_d0 + 3]; prm.d0_wo = d_in[I_d0 + 4]; prm.d0_bo = d_in[I_d0 + 5];
    prm.tg = d_in[I_tg + 0]; prm.tb = d_in[I_tg + 1]; prm.tpw = d_in[I_tg + 2];
    prm.tpb = d_in[I_tg + 3]; prm.tdw = d_in[I_tg + 4]; prm.tdb = d_in[I_tg + 5];
    prm.wsw = d_in[I_ws + 0]; prm.wb = d_in[I_ws + 1];
    prm.out = d_out;
    prm.W = (float*)d_ws;

    init_ws<<<32, 256, 0, stream>>>((float*)d_ws);
    void* args[] = { (void*)&prm };
    hipLaunchCooperativeKernel((const void*)higcn4, dim3(NBLK), dim3(NTHR), args, 0, stream);
}

// Round 7
// 1104.191 us; speedup vs baseline: 2.1820x; 1.0395x over previous
//
#include <hip/hip_runtime.h>
#include <hip/hip_bf16.h>
#include <math.h>

using bf16 = __hip_bfloat16;

#define H_IMG 128
#define W_IMG 128
#define C_IN  200
#define NCLS  16
#define N0    16384
#define N1    4096
#define N2    1024
#define KNB   16
#define EPS   1e-5f
#define SLOPE 0.01f

#define NBLK  256
#define NTHR  512
#define GSZ   (NBLK * NTHR)   // 131072 threads, 2048 waves

// barrier int slots (128B apart where contended)
#define ROOT0 0
#define REL0  32
#define GRP0  64          // 32 groups: 64 + g*32

__device__ __forceinline__ float leaky(float v) { return v >= 0.f ? v : SLOPE * v; }
__device__ __forceinline__ float cv(float v) { return v; }
__device__ __forceinline__ float cv(bf16 v) { return __bfloat162float(v); }
__device__ __forceinline__ void stv(float* p, long i, float v) { p[i] = v; }
__device__ __forceinline__ void stv(bf16* p, long i, float v) { p[i] = __float2bfloat16(v); }
__device__ __forceinline__ void atomAdd(float* p, float v) { unsafeAtomicAdd(p, v); }

// LLC-resident (cross-XCD coherent) accesses: sc0 sc1, bypass L1/L2
__device__ __forceinline__ float ldsc(const float* p) {
    return __hip_atomic_load((float*)p, __ATOMIC_RELAXED, __HIP_MEMORY_SCOPE_AGENT);
}
__device__ __forceinline__ void stsc(float* p, float v) {
    __hip_atomic_store(p, v, __ATOMIC_RELAXED, __HIP_MEMORY_SCOPE_AGENT);
}
__device__ __forceinline__ int aadd(int* p) {
    return __hip_atomic_fetch_add(p, 1, __ATOMIC_RELAXED, __HIP_MEMORY_SCOPE_AGENT);
}
__device__ __forceinline__ int ald(const int* p) {
    return __hip_atomic_load((int*)p, __ATOMIC_RELAXED, __HIP_MEMORY_SCOPE_AGENT);
}

struct Params {
    const void *x; const int *nbr_a, *nbr_b;
    const void *hg,*hb,*hpw,*hpb,*hdw,*hdb;
    const void *e0_g,*e0_b,*e0_wt,*e0_bt,*e0_wo,*e0_bo;
    const void *e1_g,*e1_b,*e1_wt,*e1_bt,*e1_wo,*e1_bo;
    const void *d0_g,*d0_b,*d0_wt,*d0_bt,*d0_wo,*d0_bo;
    const void *tg,*tb,*tpw,*tpb,*tdw,*tdb,*wsw,*wb;
    void* out; float* W;
};

// fence-free grid barrier: all data traffic is LLC-coherent by construction,
// so no buffer_wbl2/buffer_inv needed — just drain (waitcnt) + count + poll.
__device__ __forceinline__ void gbar(int* ib, int gen) {
    __syncthreads();
    if (threadIdx.x == 0) {
        __builtin_amdgcn_s_waitcnt(0);   // all prior sc-stores visible at LLC
        int g = blockIdx.x >> 3;
        int prev = aadd(&ib[GRP0 + g * 32]);
        if (prev == gen * 8 - 1) {
            int r = aadd(&ib[ROOT0]);
            if (r == gen * 32 - 1)
                __hip_atomic_store(&ib[REL0], gen, __ATOMIC_RELAXED, __HIP_MEMORY_SCOPE_AGENT);
        }
        while (ald(&ib[REL0]) < gen) __builtin_amdgcn_s_sleep(1);
    }
    __syncthreads();
}

// ---------------- derive alpha/beta from LLC sums into LDS ----------------
template <typename T>
__device__ __forceinline__ void derive_ab(const float* gs, const float* gq, const T* g, const T* bb,
                                          int C, float invP, float rep, float* la, float* lb, int t) {
    if (t < C) {
        float mu = ldsc(&gs[t]) * rep * invP;
        float var = ldsc(&gq[t]) * rep * invP - mu * mu;
        float a = rsqrtf(var + EPS) * cv(g[t]);
        la[t] = a; lb[t] = cv(bb[t]) - mu * a;
    }
    __syncthreads();
}

// ---------------- stage A: stats over x ----------------
template <typename T>
__device__ void statsX(const T* x, float* gs, float* gq, int b, int t) {
    if (t < C_IN) {
        float s = 0.f, q = 0.f;
        int r0 = b * (N0 / NBLK);
        for (int r = 0; r < N0 / NBLK; r++) {
            float v = cv(x[(long)(r0 + r) * C_IN + t]);
            s += v; q += v * v;
        }
        atomAdd(&gs[t], s); atomAdd(&gq[t], q);
    }
}

// ---------------- stage C: head dw 5x5 + pool4 + fused stats (H1, enc0) ----------------
template <typename T>
__device__ void dw_head(const float* In, const T* dwp, const T* dbp, float* R1, float* H1,
                        float* gsH, float* gqH, float* gsR, float* gqR,
                        int gtid, int t, float* sm1, float* sm2) {
    const int o = gtid & 127;
    float wr[25];
#pragma unroll
    for (int i = 0; i < 25; i++) wr[i] = cv(dwp[o * 25 + i]);
    float bias = cv(dbp[o]);
    float sH = 0.f, qH = 0.f, sR = 0.f, qR = 0.f;
    for (long e = gtid; e < (long)(N0 / 4) * 128; e += GSZ) {
        int n = (int)(e >> 7);
        int pp0 = n << 2;
        int h = pp0 >> 7, w0 = pp0 & 127;
        float pooled = 0.f;
#pragma unroll
        for (int k = 0; k < 4; k++) {
            int w = w0 + k;
            float acc = bias;
#pragma unroll
            for (int dh = -2; dh <= 2; dh++) {
                int hh = h + dh;
                if ((unsigned)hh >= 128u) continue;
#pragma unroll
                for (int dv = -2; dv <= 2; dv++) {
                    int ww = w + dv;
                    if ((unsigned)ww >= 128u) continue;
                    acc = fmaf(ldsc(&In[(long)(((hh << 7) + ww) << 7) + o]), wr[(dh + 2) * 5 + (dv + 2)], acc);
                }
            }
            float lk = leaky(acc);
            stsc(&R1[(long)(pp0 + k) * 128 + o], lk);
            sR += lk; qR += lk * lk; pooled += lk;
        }
        pooled *= 0.25f;
        stsc(&H1[(long)n * 128 + o], pooled);
        sH += pooled; qH += pooled * pooled;
    }
    sm1[t] = sH; sm2[t] = qH; __syncthreads();
    if (t < 256) { sm1[t] += sm1[t + 256]; sm2[t] += sm2[t + 256]; } __syncthreads();
    if (t < 128) { atomAdd(&gsH[t], sm1[t] + sm1[t + 128]); atomAdd(&gqH[t], sm2[t] + sm2[t + 128]); }
    __syncthreads();
    sm1[t] = sR; sm2[t] = qR; __syncthreads();
    if (t < 256) { sm1[t] += sm1[t + 256]; sm2[t] += sm2[t + 256]; } __syncthreads();
    if (t < 128) { atomAdd(&gsR[t], sm1[t] + sm1[t + 128]); atomAdd(&gqR[t], sm2[t] + sm2[t + 128]); }
    __syncthreads();
}

// ---------------- generic 2-col GEMM with inline BN (In via LLC, weights cached) ----------------
template <typename TW, int CI, int CO>
__device__ void std_gemm(const float* In, const TW* w, const TW* bias, float* Out,
                         const float* la, const float* lb, int N, int gtid) {
    const int HALF = CO / 2;
    for (long i = gtid; i < (long)N * HALF; i += GSZ) {
        int n = (int)(i / HALF);
        int j0 = (int)(i - (long)n * HALF);
        const float* in = In + (long)n * CI;
        float a0 = cv(bias[j0]), a1 = cv(bias[j0 + HALF]);
#pragma unroll 8
        for (int c = 0; c < CI; c++) {
            float v = fmaf(ldsc(&in[c]), la[c], lb[c]);
            a0 = fmaf(v, cv(w[(long)c * CO + j0]), a0);
            a1 = fmaf(v, cv(w[(long)c * CO + j0 + HALF]), a1);
        }
        stsc(&Out[(long)n * CO + j0], a0);
        stsc(&Out[(long)n * CO + j0 + HALF], a1);
    }
}

// ---------------- concat-input 2-col GEMM (d0 layer; weights cached) ----------------
template <typename TW, int C1, int C2, int CO>
__device__ void cat_gemm(const float* A, const float* B, const TW* w, const TW* bias, float* Out,
                         const float* la, const float* lb, int N, int gtid) {
    const int HALF = CO / 2;
    for (long i = gtid; i < (long)N * HALF; i += GSZ) {
        int n = (int)(i / HALF);
        int j0 = (int)(i - (long)n * HALF);
        const float* a = A + (long)(n >> 2) * C1;
        const float* bb = B + (long)n * C2;
        float a0 = cv(bias[j0]), a1 = cv(bias[j0 + HALF]);
#pragma unroll 8
        for (int c = 0; c < C1; c++) {
            float v = fmaf(ldsc(&a[c]), la[c], lb[c]);
            a0 = fmaf(v, cv(w[(long)c * CO + j0]), a0);
            a1 = fmaf(v, cv(w[(long)c * CO + j0 + HALF]), a1);
        }
#pragma unroll 8
        for (int c = 0; c < C2; c++) {
            float v = fmaf(ldsc(&bb[c]), la[C1 + c], lb[C1 + c]);
            a0 = fmaf(v, cv(w[(long)(C1 + c) * CO + j0]), a0);
            a1 = fmaf(v, cv(w[(long)(C1 + c) * CO + j0 + HALF]), a1);
        }
        stsc(&Out[(long)n * CO + j0], a0);
        stsc(&Out[(long)n * CO + j0 + HALF], a1);
    }
}

// ---------------- attention node (one wave = one node; LLC reads) ----------------
template <int CO>
__device__ __forceinline__ float attn_node(const float* th, const float* ou, const int* nbr, int n, int lane) {
    float r0 = ldsc(&th[(long)n * 128 + lane]);
    float r1 = ldsc(&th[(long)n * 128 + 64 + lane]);
    int mk[KNB]; float av[KNB];
#pragma unroll
    for (int k = 0; k < KNB; k++) {
        int m = nbr[n * KNB + k]; mk[k] = m;
        float v = fmaf(r0, ldsc(&th[(long)m * 128 + lane]), r1 * ldsc(&th[(long)m * 128 + 64 + lane]));
#pragma unroll
        for (int off = 32; off > 0; off >>= 1) v += __shfl_xor(v, off, 64);
        av[k] = 1.f / (1.f + expf(-v));
    }
    float amax = av[0];
#pragma unroll
    for (int k = 1; k < KNB; k++) amax = fmaxf(amax, av[k]);
    float den = 0.f;
#pragma unroll
    for (int k = 0; k < KNB; k++) { av[k] = expf(av[k] - amax); den += av[k]; }
    float acc = 0.f;
    if (lane < CO) {
#pragma unroll
        for (int k = 0; k < KNB; k++) acc = fmaf(av[k], ldsc(&ou[(long)mk[k] * CO + lane]), acc);
    }
    return leaky(acc / den);
}

__device__ void attn_e0(const float* TH_, const float* OU_, const int* nbr, float* E1, float* H2,
                        float* gsH2, float* gqH2, float* gsE, float* gqE, int gtid) {
    int lane = gtid & 63, wv = gtid >> 6;
    if (wv < N1 / 4) {
        float sE = 0.f, qE = 0.f, pooled = 0.f;
#pragma unroll
        for (int k = 0; k < 4; k++) {
            int n = (wv << 2) + k;
            float v = attn_node<64>(TH_, OU_, nbr, n, lane);
            stsc(&E1[(long)n * 64 + lane], v);
            sE += v; qE += v * v; pooled += v;
        }
        pooled *= 0.25f;
        stsc(&H2[(long)wv * 64 + lane], pooled);
        atomAdd(&gsE[lane], sE); atomAdd(&gqE[lane], qE);
        atomAdd(&gsH2[lane], pooled); atomAdd(&gqH2[lane], pooled * pooled);
    }
}

__device__ void attn_e1(const float* TH_, const float* OU_, const int* nbr, float* HD,
                        float* gs, float* gq, int gtid) {
    int lane = gtid & 63, wv = gtid >> 6;
    if (wv < N2) {
        float v = attn_node<32>(TH_, OU_, nbr, wv, lane);
        if (lane < 32) {
            stsc(&HD[(long)wv * 32 + lane], v);
            atomAdd(&gs[lane], v); atomAdd(&gq[lane], v * v);
        }
    }
}

__device__ void attn_d0(const float* TH_, const float* OU_, const int* nbr, float* HDE,
                        float* gs, float* gq, int gtid) {
    int lane = gtid & 63, wv = gtid >> 6;
    float s = 0.f, q = 0.f;
    for (int n = wv; n < N1; n += GSZ / 64) {
        float v = attn_node<64>(TH_, OU_, nbr, n, lane);
        stsc(&HDE[(long)n * 64 + lane], v);
        s += v; q += v * v;
    }
    atomAdd(&gs[lane], s); atomAdd(&gq[lane], q);
}

// ---------------- stage O': tail dw + classifier fused via LDS ----------------
template <typename T>
__device__ void dw_cls(const float* In, const T* dwp, const T* dbp, const T* wsw, const T* wb,
                       T* out, int b, int t, float* sm1) {
    const int o = t & 127;
    float wr[25];
#pragma unroll
    for (int i = 0; i < 25; i++) wr[i] = cv(dwp[o * 25 + i]);
    float bias = cv(dbp[o]);
    for (int it = 0; it < (N0 * 128) / GSZ; it++) {  // 16
        long ebase = (long)it * GSZ + (long)b * NTHR;
        int p = (int)((ebase + t) >> 7);
        int h = p >> 7, w = p & 127;
        float acc = bias;
#pragma unroll
        for (int dh = -2; dh <= 2; dh++) {
            int hh = h + dh;
            if ((unsigned)hh >= 128u) continue;
#pragma unroll
            for (int dv = -2; dv <= 2; dv++) {
                int ww = w + dv;
                if ((unsigned)ww >= 128u) continue;
                acc = fmaf(ldsc(&In[(long)(((hh << 7) + ww) << 7) + o]), wr[(dh + 2) * 5 + (dv + 2)], acc);
            }
        }
        sm1[t] = leaky(acc);
        __syncthreads();
        if (t < (NTHR / 128) * 16) {   // 64 threads: 4 pixels x 16 classes
            int r = t >> 4, j = t & 15;
            const float* Fv = sm1 + r * 128;
            float lg = cv(wb[j]);
#pragma unroll 4
            for (int c = 0; c < 128; c++) lg = fmaf(Fv[c], cv(wsw[c * 16 + j]), lg);
            float m = lg;
#pragma unroll
            for (int s = 8; s > 0; s >>= 1) m = fmaxf(m, __shfl_xor(m, s, 16));
            float ex = expf(lg - m);
            float d = ex;
#pragma unroll
            for (int s = 8; s > 0; s >>= 1) d += __shfl_xor(d, s, 16);
            int p0 = (int)(ebase >> 7);
            stv(out, (long)(p0 + r) * 16 + j, ex / d);
        }
        __syncthreads();
    }
}

// ================= main cooperative kernel =================
__global__ __launch_bounds__(NTHR) void higcn5(Params p) {
    const int t = threadIdx.x, b = blockIdx.x;
    const int gtid = b * NTHR + t;
    __shared__ float sm1[NTHR], sm2[NTHR];
    __shared__ float wlds[200 * 129];   // staged+transposed 1x1-conv weights (head/tail), pad 129

    float* W = p.W;
    int* ib = (int*)W;                            // barrier state: ints [0..2047]
    float* A0 = W + 2048; float* A1 = W + 2304;   // x sums (200)
    float* A2 = W + 2560; float* A3 = W + 2816;   // H1 sums (128)
    float* A4 = W + 3072; float* A5 = W + 3328;   // H2 sums (64)
    float* A6 = W + 3584; float* A7 = W + 3840;   // cat1 sums (96: 0..31 HD, 32..95 E1)
    float* A8 = W + 4096; float* A9 = W + 4352;   // cat2 sums (192: 0..63 HDE, 64..191 enc0)
    float* R0  = W + 65536;                       // 16384x128
    float* R1  = R0 + (long)N0 * 128;             // 16384x128 (enc0)
    float* H1  = R1 + (long)N0 * 128;             // 4096x128
    float* TH  = H1 + (long)N1 * 128;             // 4096x128
    float* OU  = TH + (long)N1 * 128;             // 4096x64
    float* E1  = OU + (long)N1 * 64;              // 4096x64
    float* H2  = E1 + (long)N1 * 64;              // 1024x64
    float* HD  = H2 + (long)N2 * 64;              // 1024x32
    float* HDE = HD + (long)N2 * 32;              // 4096x64

    // dtype detect (per-block)
    {
        const unsigned short* u = (const unsigned short*)p.x;
        int cn = 0;
        for (int i = t; i < 4096; i += NTHR) cn += (((u[i] >> 7) & 0xFF) >= 0xC0);
        sm1[t] = (float)cn; __syncthreads();
        for (int k = NTHR / 2; k > 0; k >>= 1) { if (t < k) sm1[t] += sm1[t + k]; __syncthreads(); }
    }
    const bool F32 = sm1[0] > 32.f;
    __syncthreads();
    int gen = 0;

    // A: stats(x)
    if (F32) statsX((const float*)p.x, A0, A1, b, t);
    else     statsX((const bf16*)p.x, A0, A1, b, t);
    gbar(ib, ++gen);

    // B: head GEMM 16384x200 -> 128 (weights staged+transposed into LDS)
    if (F32) {
        derive_ab(A0, A1, (const float*)p.hg, (const float*)p.hb, 200, 1.f / N0, 1.f, sm1, sm2, t);
        const float* hw = (const float*)p.hpw;
        for (int i = t; i < 128 * 200; i += NTHR) { int j = i / 200, c = i - j * 200; wlds[c * 129 + j] = hw[i]; }
        __syncthreads();
        const float* x = (const float*)p.x; const float* bias = (const float*)p.hpb;
        for (long i = gtid; i < (long)N0 * 64; i += GSZ) {
            int n = (int)(i >> 6), j0 = (int)(i & 63);
            const float* in = x + (long)n * C_IN;
            float a0 = bias[j0], a1 = bias[j0 + 64];
#pragma unroll 8
            for (int c = 0; c < C_IN; c++) {
                float v = fmaf(in[c], sm1[c], sm2[c]);
                a0 = fmaf(v, wlds[c * 129 + j0], a0);
                a1 = fmaf(v, wlds[c * 129 + j0 + 64], a1);
            }
            stsc(&R0[(long)n * 128 + j0], leaky(a0));
            stsc(&R0[(long)n * 128 + j0 + 64], leaky(a1));
        }
    } else {
        derive_ab(A0, A1, (const bf16*)p.hg, (const bf16*)p.hb, 200, 1.f / N0, 1.f, sm1, sm2, t);
        const bf16* hw = (const bf16*)p.hpw;
        for (int i = t; i < 128 * 200; i += NTHR) { int j = i / 200, c = i - j * 200; wlds[c * 129 + j] = cv(hw[i]); }
        __syncthreads();
        const bf16* x = (const bf16*)p.x; const bf16* bias = (const bf16*)p.hpb;
        for (long i = gtid; i < (long)N0 * 64; i += GSZ) {
            int n = (int)(i >> 6), j0 = (int)(i & 63);
            const bf16* in = x + (long)n * C_IN;
            float a0 = cv(bias[j0]), a1 = cv(bias[j0 + 64]);
#pragma unroll 8
            for (int c = 0; c < C_IN; c++) {
                float v = fmaf(cv(in[c]), sm1[c], sm2[c]);
                a0 = fmaf(v, wlds[c * 129 + j0], a0);
                a1 = fmaf(v, wlds[c * 129 + j0 + 64], a1);
            }
            stsc(&R0[(long)n * 128 + j0], leaky(a0));
            stsc(&R0[(long)n * 128 + j0 + 64], leaky(a1));
        }
    }
    gbar(ib, ++gen);

    // C: head dw + pool + stats(H1) + stats(enc0 -> cat2[64..191])
    if (F32) dw_head(R0, (const float*)p.hdw, (const float*)p.hdb, R1, H1, A2, A3, A8 + 64, A9 + 64, gtid, t, sm1, sm2);
    else     dw_head(R0, (const bf16*)p.hdw, (const bf16*)p.hdb, R1, H1, A2, A3, A8 + 64, A9 + 64, gtid, t, sm1, sm2);
    gbar(ib, ++gen);

    // E: e0 GEMMs
    if (F32) {
        derive_ab(A2, A3, (const float*)p.e0_g, (const float*)p.e0_b, 128, 1.f / N1, 1.f, sm1, sm2, t);
        std_gemm<float, 128, 128>(H1, (const float*)p.e0_wt, (const float*)p.e0_bt, TH, sm1, sm2, N1, gtid);
        std_gemm<float, 128, 64>(H1, (const float*)p.e0_wo, (const float*)p.e0_bo, OU, sm1, sm2, N1, gtid);
    } else {
        derive_ab(A2, A3, (const bf16*)p.e0_g, (const bf16*)p.e0_b, 128, 1.f / N1, 1.f, sm1, sm2, t);
        std_gemm<bf16, 128, 128>(H1, (const bf16*)p.e0_wt, (const bf16*)p.e0_bt, TH, sm1, sm2, N1, gtid);
        std_gemm<bf16, 128, 64>(H1, (const bf16*)p.e0_wo, (const bf16*)p.e0_bo, OU, sm1, sm2, N1, gtid);
    }
    gbar(ib, ++gen);

    // F: attn e0 + pool + stats(H2) + stats(E1 -> cat1[32..95])
    attn_e0(TH, OU, p.nbr_a, E1, H2, A4, A5, A6 + 32, A7 + 32, gtid);
    gbar(ib, ++gen);

    // H: e1 GEMMs
    if (F32) {
        derive_ab(A4, A5, (const float*)p.e1_g, (const float*)p.e1_b, 64, 1.f / N2, 1.f, sm1, sm2, t);
        std_gemm<float, 64, 128>(H2, (const float*)p.e1_wt, (const float*)p.e1_bt, TH, sm1, sm2, N2, gtid);
        std_gemm<float, 64, 32>(H2, (const float*)p.e1_wo, (const float*)p.e1_bo, OU, sm1, sm2, N2, gtid);
    } else {
        derive_ab(A4, A5, (const bf16*)p.e1_g, (const bf16*)p.e1_b, 64, 1.f / N2, 1.f, sm1, sm2, t);
        std_gemm<bf16, 64, 128>(H2, (const bf16*)p.e1_wt, (const bf16*)p.e1_bt, TH, sm1, sm2, N2, gtid);
        std_gemm<bf16, 64, 32>(H2, (const bf16*)p.e1_wo, (const bf16*)p.e1_bo, OU, sm1, sm2, N2, gtid);
    }
    gbar(ib, ++gen);

    // I: attn e1 + stats(HD -> cat1[0..31])
    attn_e1(TH, OU, p.nbr_b, HD, A6, A7, gtid);
    gbar(ib, ++gen);

    // K: d0 GEMMs (virtual concat)
    if (F32) {
        derive_ab(A6, A7, (const float*)p.d0_g, (const float*)p.d0_b, 32, 1.f / N1, 4.f, sm1, sm2, t);
        derive_ab(A6 + 32, A7 + 32, ((const float*)p.d0_g) + 32, ((const float*)p.d0_b) + 32, 64, 1.f / N1, 1.f, sm1 + 32, sm2 + 32, t);
        cat_gemm<float, 32, 64, 128>(HD, E1, (const float*)p.d0_wt, (const float*)p.d0_bt, TH, sm1, sm2, N1, gtid);
        cat_gemm<float, 32, 64, 64>(HD, E1, (const float*)p.d0_wo, (const float*)p.d0_bo, OU, sm1, sm2, N1, gtid);
    } else {
        derive_ab(A6, A7, (const bf16*)p.d0_g, (const bf16*)p.d0_b, 32, 1.f / N1, 4.f, sm1, sm2, t);
        derive_ab(A6 + 32, A7 + 32, ((const bf16*)p.d0_g) + 32, ((const bf16*)p.d0_b) + 32, 64, 1.f / N1, 1.f, sm1 + 32, sm2 + 32, t);
        cat_gemm<bf16, 32, 64, 128>(HD, E1, (const bf16*)p.d0_wt, (const bf16*)p.d0_bt, TH, sm1, sm2, N1, gtid);
        cat_gemm<bf16, 32, 64, 64>(HD, E1, (const bf16*)p.d0_wo, (const bf16*)p.d0_bo, OU, sm1, sm2, N1, gtid);
    }
    gbar(ib, ++gen);

    // L: attn d0 + stats(HDE -> cat2[0..63])
    attn_d0(TH, OU, p.nbr_a, HDE, A8, A9, gtid);
    gbar(ib, ++gen);

    // N: tail GEMM (virtual concat [HDE rep4 | enc0], weights staged+transposed into LDS)
    {
        if (F32) {
            derive_ab(A8, A9, (const float*)p.tg, (const float*)p.tb, 64, 1.f / N0, 4.f, sm1, sm2, t);
            derive_ab(A8 + 64, A9 + 64, ((const float*)p.tg) + 64, ((const float*)p.tb) + 64, 128, 1.f / N0, 1.f, sm1 + 64, sm2 + 64, t);
            const float* tw = (const float*)p.tpw;
            for (int i = t; i < 128 * 192; i += NTHR) { int j = i / 192, c = i - j * 192; wlds[c * 129 + j] = tw[i]; }
        } else {
            derive_ab(A8, A9, (const bf16*)p.tg, (const bf16*)p.tb, 64, 1.f / N0, 4.f, sm1, sm2, t);
            derive_ab(A8 + 64, A9 + 64, ((const bf16*)p.tg) + 64, ((const bf16*)p.tb) + 64, 128, 1.f / N0, 1.f, sm1 + 64, sm2 + 64, t);
            const bf16* tw = (const bf16*)p.tpw;
            for (int i = t; i < 128 * 192; i += NTHR) { int j = i / 192, c = i - j * 192; wlds[c * 129 + j] = cv(tw[i]); }
        }
        __syncthreads();
        for (long i = gtid; i < (long)N0 * 64; i += GSZ) {
            int n = (int)(i >> 6), j0 = (int)(i & 63);
            const float* hd = HDE + (long)(n >> 2) * 64;
            const float* h0 = R1 + (long)n * 128;
            float a0, a1;
            if (F32) { a0 = ((const float*)p.tpb)[j0]; a1 = ((const float*)p.tpb)[j0 + 64]; }
            else { a0 = cv(((const bf16*)p.tpb)[j0]); a1 = cv(((const bf16*)p.tpb)[j0 + 64]); }
#pragma unroll 8
            for (int c = 0; c < 64; c++) {
                float v = fmaf(ldsc(&hd[c]), sm1[c], sm2[c]);
                a0 = fmaf(v, wlds[c * 129 + j0], a0);
                a1 = fmaf(v, wlds[c * 129 + j0 + 64], a1);
            }
#pragma unroll 8
            for (int c = 0; c < 128; c++) {
                float v = fmaf(ldsc(&h0[c]), sm1[64 + c], sm2[64 + c]);
                a0 = fmaf(v, wlds[(64 + c) * 129 + j0], a0);
                a1 = fmaf(v, wlds[(64 + c) * 129 + j0 + 64], a1);
            }
            stsc(&R0[(long)n * 128 + j0], leaky(a0));
            stsc(&R0[(long)n * 128 + j0 + 64], leaky(a1));
        }
    }
    gbar(ib, ++gen);

    // O': tail dw + classifier
    if (F32) dw_cls(R0, (const float*)p.tdw, (const float*)p.tdb, (const float*)p.wsw, (const float*)p.wb, (float*)p.out, b, t, sm1);
    else     dw_cls(R0, (const bf16*)p.tdw, (const bf16*)p.tdb, (const bf16*)p.wsw, (const bf16*)p.wb, (bf16*)p.out, b, t, sm1);
}

// ---------------- init: zero barrier + accumulators ----------------
__global__ void init_ws(float* W) {
    int i = blockIdx.x * 256 + threadIdx.x;
    if (i < 8192) W[i] = 0.f;
}

// ================= host side =================
extern "C" void kernel_launch(void* const* d_in, const int* in_sizes, int n_in,
                              void* d_out, int out_size, void* d_ws, size_t ws_size,
                              hipStream_t stream) {
    bool dict = (in_sizes[1] > 1000000);
    int I_x, I_nbr_a, I_nbr_b, I_hg, I_ws, I_e0, I_e1, I_d0, I_tg;
    if (dict) {
        I_x = 0; I_nbr_a = 5; I_nbr_b = 6; I_hg = 7; I_e0 = 13; I_e1 = 19; I_d0 = 25; I_tg = 31; I_ws = 37;
    } else {
        I_x = 0; I_hg = 1; I_e0 = 7; I_e1 = 13; I_d0 = 19; I_tg = 25; I_ws = 31; I_nbr_a = 37; I_nbr_b = 38;
    }
    Params prm;
    prm.x = d_in[I_x];
    prm.nbr_a = (const int*)d_in[I_nbr_a];
    prm.nbr_b = (const int*)d_in[I_nbr_b];
    prm.hg = d_in[I_hg + 0]; prm.hb = d_in[I_hg + 1]; prm.hpw = d_in[I_hg + 2];
    prm.hpb = d_in[I_hg + 3]; prm.hdw = d_in[I_hg + 4]; prm.hdb = d_in[I_hg + 5];
    prm.e0_g = d_in[I_e0 + 0]; prm.e0_b = d_in[I_e0 + 1]; prm.e0_wt = d_in[I_e0 + 2];
    prm.e0_bt = d_in[I_e0 + 3]; prm.e0_wo = d_in[I_e0 + 4]; prm.e0_bo = d_in[I_e0 + 5];
    prm.e1_g = d_in[I_e1 + 0]; prm.e1_b = d_in[I_e1 + 1]; prm.e1_wt = d_in[I_e1 + 2];
    prm.e1_bt = d_in[I_e1 + 3]; prm.e1_wo = d_in[I_e1 + 4]; prm.e1_bo = d_in[I_e1 + 5];
    prm.d0_g = d_in[I_d0 + 0]; prm.d0_b = d_in[I_d0 + 1]; prm.d0_wt = d_in[I_d0 + 2];
    prm.d0_bt = d_in[I_d0 + 3]; prm.d0_wo = d_in[I_d0 + 4]; prm.d0_bo = d_in[I_d0 + 5];
    prm.tg = d_in[I_tg + 0]; prm.tb = d_in[I_tg + 1]; prm.tpw = d_in[I_tg + 2];
    prm.tpb = d_in[I_tg + 3]; prm.tdw = d_in[I_tg + 4]; prm.tdb = d_in[I_tg + 5];
    prm.wsw = d_in[I_ws + 0]; prm.wb = d_in[I_ws + 1];
    prm.out = d_out;
    prm.W = (float*)d_ws;

    init_ws<<<32, 256, 0, stream>>>((float*)d_ws);
    void* args[] = { (void*)&prm };
    hipLaunchCooperativeKernel((const void*)higcn5, dim3(NBLK), dim3(NTHR), args, 0, stream);
}